// Round 12
// baseline (346.738 us; speedup 1.0000x reference)
//
#include <hip/hip_runtime.h>
#include <hip/hip_bf16.h>

typedef unsigned short u16;
typedef unsigned int u32;
typedef __attribute__((ext_vector_type(8))) short bf16x8;
typedef __attribute__((ext_vector_type(4))) float f32x4;
typedef __attribute__((ext_vector_type(16))) float f32x16;

#define DEV __device__ __forceinline__
#define FENCE asm volatile("" ::: "memory")
#define BAR __builtin_amdgcn_s_barrier()
#define VMC(n) asm volatile("s_waitcnt vmcnt(" #n ")" ::: "memory")
#define LGKM(n) asm volatile("s_waitcnt lgkmcnt(" #n ")" ::: "memory")
#define SGB __builtin_amdgcn_sched_barrier(0)

static constexpr int Bc = 4, Nc = 1024, Dc = 1024, Hc = 16, Mc = 4096, D2c = 2048;
static constexpr size_t VT_STRIDE = (size_t)4 * 16 * 64 * 1024;  // per-stream vt elems

DEV u16 f2bf(float f) {
  u32 u = __builtin_bit_cast(u32, f);
  u = (u + 0x7FFFu + ((u >> 16) & 1u)) >> 16;
  return (u16)u;
}
DEV float bf2f(u16 h) { u32 u = ((u32)h) << 16; return __builtin_bit_cast(float, u); }
DEV void gl_lds16(const void* g, void* l) {
  __builtin_amdgcn_global_load_lds((const __attribute__((address_space(1))) u32*)g,
                                   (__attribute__((address_space(3))) u32*)l, 16, 0, 0);
}
// deep swizzle for k_attn: separates rows 8 apart (row-stride 128B == bank cycle)
DEV int SW(int r, int c) { return c ^ (r & 7) ^ ((r >> 3) & 3); }

// exact-class erf: Abramowitz-Stegun 7.1.26, |err| < 1.5e-7
DEV float erf_fast(float x) {
  float ax = __builtin_fabsf(x);
  float t = __builtin_amdgcn_rcpf(__builtin_fmaf(0.3275911f, ax, 1.0f));
  float p = __builtin_fmaf(1.061405429f, t, -1.453152027f);
  p = __builtin_fmaf(p, t, 1.421413741f);
  p = __builtin_fmaf(p, t, -0.284496736f);
  p = __builtin_fmaf(p, t, 0.254829592f);
  p *= t;
  float e = __builtin_amdgcn_exp2f(-1.4426950408889634f * ax * ax);  // exp(-x^2)
  float r = __builtin_fmaf(-p, e, 1.0f);
  return __builtin_copysignf(r, x);
}
DEV float gelu_exact(float v) {
  return 0.5f * v * (1.0f + erf_fast(v * 0.70710678118654752f));
}

// ---------------- fp32 -> bf16 convert (vectorized) ----------------
__global__ __launch_bounds__(256) void k_f32_to_bf16(const float* __restrict__ in,
                                                     u16* __restrict__ out, int n) {
  int i = (blockIdx.x * 256 + threadIdx.x) * 8;
  if (i >= n) return;
  float4 a = *(const float4*)(in + i);
  float4 b = *(const float4*)(in + i + 4);
  union { u16 s[8]; uint4 v; } r;
  r.s[0] = f2bf(a.x); r.s[1] = f2bf(a.y); r.s[2] = f2bf(a.z); r.s[3] = f2bf(a.w);
  r.s[4] = f2bf(b.x); r.s[5] = f2bf(b.y); r.s[6] = f2bf(b.z); r.s[7] = f2bf(b.w);
  *(uint4*)(out + i) = r.v;
}

// ---------------- fp32 [R][C] -> bf16 [C][R] transpose-convert ----------------
__global__ __launch_bounds__(256) void k_transpose_f32_bf16(const float* __restrict__ in,
                                                            u16* __restrict__ out, int R, int C) {
  __shared__ float t[64][65];
  int c0 = blockIdx.x * 64, r0 = blockIdx.y * 64;
  int tid = threadIdx.x;
  int rr = tid >> 4, cc4 = (tid & 15) * 4;
  for (int k = 0; k < 4; ++k) {
    int r = rr + k * 16;
    float4 v = *(const float4*)(in + (size_t)(r0 + r) * C + c0 + cc4);
    t[r][cc4 + 0] = v.x; t[r][cc4 + 1] = v.y; t[r][cc4 + 2] = v.z; t[r][cc4 + 3] = v.w;
  }
  __syncthreads();
  int cw = tid >> 4, rr4 = (tid & 15) * 4;
  for (int k = 0; k < 4; ++k) {
    int c = cw + k * 16;
    union { u16 s[4]; uint2 v; } p;
    for (int j = 0; j < 4; ++j) p.s[j] = f2bf(t[rr4 + j][c]);
    *(uint2*)(out + (size_t)(c0 + c) * R + r0 + rr4) = p.v;
  }
}

// ---------------- v (cols 1024.. of qkv, stride 2048) -> vt [z][B*H*64, N] ----------------
__global__ __launch_bounds__(256) void k_v_transpose(const u16* __restrict__ qkv,
                                                     u16* __restrict__ vt01) {
  __shared__ __align__(16) u16 t[64][80];
  int z = blockIdx.z;
  const u16* v = qkv + (size_t)z * Mc * 2048 + 1024;
  u16* vt = vt01 + (size_t)z * VT_STRIDE;
  int nt = blockIdx.x;
  int bh = blockIdx.y, b = bh >> 4, h = bh & 15;
  int tid = threadIdx.x;
  for (int it = 0; it < 2; ++it) {
    int u = it * 256 + tid; int r = u >> 3, ch = u & 7;
    uint4 raw = *(const uint4*)(v + ((size_t)b * Nc + nt * 64 + r) * 2048 + h * 64 + ch * 8);
    *(uint4*)&t[r][ch * 8] = raw;
  }
  __syncthreads();
  for (int it = 0; it < 2; ++it) {
    int u = it * 256 + tid; int d = u >> 3, nch = u & 7;
    union { u16 s[8]; uint4 v4; } p;
    for (int j = 0; j < 8; ++j) p.s[j] = t[nch * 8 + j][d];
    *(uint4*)(vt + ((size_t)bh * 64 + d) * Nc + nt * 64 + nch * 8) = p.v4;
  }
}

// ---------------- 256x256x64 GEMM, register-pipelined gray-order phases ----------------
// Per tile, quadrants q00->q01->q11->q10; each phase issues the NEXT phase's ds_reads
// before its own MFMAs (counted lgkmcnt + sched_barrier) so LDS reads overlap MFMA.
// One barrier per phase; vmcnt gates at P1/P3/P4/P7/P8 (per-wave counted, never 0).
__global__ __launch_bounds__(512, 1) void k_gemm8(
    const u16* __restrict__ A1, int lda1, const u16* __restrict__ A2, int lda2, int kstile,
    const u16* __restrict__ Bt, const float* __restrict__ bias1, const float* __restrict__ bias2,
    int Nsplit, float scale1, float scale2, u16* __restrict__ out, int ldc, int K, int gx) {
  __shared__ __align__(16) u16 lds[65536];  // [A|B][buf][half][128*64]
  int tid = threadIdx.x;
  int w = tid >> 6, l = tid & 63;
  int lo = l & 15, hi = l >> 4;
  int wm2 = w >> 2, wn4 = w & 3;
  int nt = K >> 6, niter = nt >> 1;

  int nwg = gridDim.x;
  int swz = (blockIdx.x & 7) * (nwg >> 3) + (blockIdx.x >> 3);
  int m0 = (swz / gx) * 256, n0 = (swz % gx) * 256;

  auto ldsA = [&](int buf, int h) -> u16* { return lds + ((buf << 1) + h) * 8192; };
  auto ldsB = [&](int buf, int h) -> u16* { return lds + 32768 + ((buf << 1) + h) * 8192; };

  auto stageA = [&](int tile, int h) {
    int tt = tile < nt ? tile : 0;
    const u16* base; int ldx, kof;
    if (tt < kstile) { base = A1; ldx = lda1; kof = tt * 64; }
    else             { base = A2; ldx = lda2; kof = (tt - kstile) * 64; }
    u16* dst = ldsA(tile & 1, h);
    size_t row0 = (size_t)(m0 + h * 128);
#pragma unroll
    for (int i = 0; i < 2; ++i) {
      int e = i * 4096 + tid * 8;
      int r = e >> 6, s = (e >> 3) & 7;
      gl_lds16(base + (row0 + r) * (size_t)ldx + kof + 8 * (s ^ (r & 7)), dst + e);
    }
  };
  auto stageB = [&](int tile, int h) {
    int tt = tile < nt ? tile : 0;
    u16* dst = ldsB(tile & 1, h);
    size_t row0 = (size_t)(n0 + h * 128);
#pragma unroll
    for (int i = 0; i < 2; ++i) {
      int e = i * 4096 + tid * 8;
      int r = e >> 6, s = (e >> 3) & 7;
      gl_lds16(Bt + (row0 + r) * (size_t)K + tt * 64 + 8 * (s ^ (r & 7)), dst + e);
    }
  };
  auto loadA = [&](bf16x8 (&a)[4][2], int buf, int qm) {
    const u16* src = ldsA(buf, qm);
#pragma unroll
    for (int mf = 0; mf < 4; ++mf) {
      int r = wm2 * 64 + mf * 16 + lo;
#pragma unroll
      for (int kk = 0; kk < 2; ++kk)
        a[mf][kk] = *(const bf16x8*)&src[r * 64 + (((kk * 4 + hi) ^ (r & 7)) << 3)];
    }
  };
  auto loadB = [&](bf16x8 (&bq)[2][2], int buf, int qn) {
    const u16* src = ldsB(buf, qn);
#pragma unroll
    for (int nf = 0; nf < 2; ++nf) {
      int r = wn4 * 32 + nf * 16 + lo;
#pragma unroll
      for (int kk = 0; kk < 2; ++kk)
        bq[nf][kk] = *(const bf16x8*)&src[r * 64 + (((kk * 4 + hi) ^ (r & 7)) << 3)];
    }
  };

  f32x4 acc00[4][2] = {}, acc01[4][2] = {}, acc10[4][2] = {}, acc11[4][2] = {};
  bf16x8 a_A[4][2], a_B[4][2], b0[2][2], b1[2][2];

  // kk-outer ordering: consecutive MFMAs independent (dep distance 8)
  auto mmaQ = [&](f32x4 (&accq)[4][2], bf16x8 (&aa)[4][2], bf16x8 (&bb)[2][2]) {
    __builtin_amdgcn_s_setprio(1);
#pragma unroll
    for (int kk = 0; kk < 2; ++kk)
#pragma unroll
      for (int mf = 0; mf < 4; ++mf)
#pragma unroll
        for (int nf = 0; nf < 2; ++nf)
          accq[mf][nf] = __builtin_amdgcn_mfma_f32_16x16x32_bf16(aa[mf][kk], bb[nf][kk], accq[mf][nf], 0, 0, 0);
    __builtin_amdgcn_s_setprio(0);
  };

  // prologue: stage tiles 0,1 (16 loads); gate first 6 (A0h0,B0h0,B0h1); issue q00 frags
  stageA(0, 0); stageB(0, 0); stageB(0, 1); stageA(0, 1);
  stageA(1, 0); stageB(1, 0); stageB(1, 1); stageA(1, 1);
  VMC(10); BAR;
  loadA(a_A, 0, 0);
  loadB(b0, 0, 0);
  FENCE;

  for (int it = 0; it < niter; ++it) {
    int t0 = 2 * it;
    // P1: q00(buf0) uses a_A,b0 ; issue b1(buf0,h1)
    loadB(b1, 0, 1);
    LGKM(4); SGB;
    mmaQ(acc00, a_A, b0);
    VMC(8); BAR;
    // P2: q01 uses a_A,b1 ; issue a_B(buf0,h1) ; stage A(t0+2,h0)
    loadA(a_B, 0, 1);
    stageA(t0 + 2, 0);
    LGKM(8); SGB;
    mmaQ(acc01, a_A, b1);
    BAR;
    // P3: q11 uses a_B,b1 ; stage B(t0+2,h0)
    stageB(t0 + 2, 0);
    LGKM(0); SGB;
    mmaQ(acc11, a_B, b1);
    VMC(8); BAR;
    // P4: q10 uses a_B,b0 ; pre-issue a_A(buf1,h0) ; stage B(t0+2,h1) ; post-issue b0(buf1,h0)
    loadA(a_A, 1, 0);
    stageB(t0 + 2, 1);
    SGB;
    mmaQ(acc10, a_B, b0);
    loadB(b0, 1, 0);
    VMC(6); BAR;
    // P5: q00(buf1) uses a_A,b0 ; issue b1(buf1,h1) ; stage A(t0+2,h1)
    loadB(b1, 1, 1);
    stageA(t0 + 2, 1);
    LGKM(4); SGB;
    mmaQ(acc00, a_A, b0);
    BAR;
    // P6: q01 uses a_A,b1 ; issue a_B(buf1,h1) ; stage A(t0+3,h0)
    loadA(a_B, 1, 1);
    stageA(t0 + 3, 0);
    LGKM(8); SGB;
    mmaQ(acc01, a_A, b1);
    BAR;
    // P7: q11 uses a_B,b1 ; stage B(t0+3,h0)
    stageB(t0 + 3, 0);
    LGKM(0); SGB;
    mmaQ(acc11, a_B, b1);
    VMC(8); BAR;
    // P8: q10 uses a_B,b0 ; pre-issue a_A(buf0 next,h0) ; stage B,A(t0+3,h1) ; post-issue b0
    loadA(a_A, 0, 0);
    stageB(t0 + 3, 1); stageA(t0 + 3, 1);
    SGB;
    mmaQ(acc10, a_B, b0);
    loadB(b0, 0, 0);
    VMC(10); BAR;
  }

  auto epi = [&](f32x4 (&accq)[4][2], int qm, int qn) {
#pragma unroll
    for (int mf = 0; mf < 4; ++mf)
#pragma unroll
      for (int nf = 0; nf < 2; ++nf) {
        int col = n0 + qn * 128 + wn4 * 32 + nf * 16 + lo;
        float bb, sc;
        if (col < Nsplit) { bb = bias1[col]; sc = scale1; }
        else              { bb = bias2[col - Nsplit]; sc = scale2; }
        int row = m0 + qm * 128 + wm2 * 64 + mf * 16 + hi * 4;
#pragma unroll
        for (int i = 0; i < 4; ++i)
          out[(size_t)(row + i) * ldc + col] = f2bf((accq[mf][nf][i] + bb) * sc);
      }
  };
  epi(acc00, 0, 0); epi(acc01, 0, 1); epi(acc11, 1, 1); epi(acc10, 1, 0);
}

// ---------------- 256x128x64 variant, same register-pipelined schedule ----------------
// A-half = 2 gl_lds, B-half = 1. Gates: P1/P3/P7 -> VMC(6), P4 -> VMC(4), P8 -> VMC(8).
template <bool OUT_BF16>
__global__ __launch_bounds__(512, 1) void k_gemm8h(
    const u16* __restrict__ A1, int lda1, const u16* __restrict__ Bt,
    const float* __restrict__ bias,
    const float* __restrict__ resid0, const float* __restrict__ resid1, int Msplit,
    void* __restrict__ out, int ldc, int K, int gx) {
  __shared__ __align__(16) u16 lds[49152];  // A: 2buf*2half*8192, B: 2buf*2half*4096
  int tid = threadIdx.x;
  int w = tid >> 6, l = tid & 63;
  int lo = l & 15, hi = l >> 4;
  int wm2 = w >> 2, wn4 = w & 3;
  int nt = K >> 6, niter = nt >> 1;

  int nwg = gridDim.x;
  int swz = (blockIdx.x & 7) * (nwg >> 3) + (blockIdx.x >> 3);
  int m0 = (swz / gx) * 256, n0 = (swz % gx) * 128;

  auto ldsA = [&](int buf, int h) -> u16* { return lds + ((buf << 1) + h) * 8192; };
  auto ldsB = [&](int buf, int h) -> u16* { return lds + 32768 + ((buf << 1) + h) * 4096; };

  auto stageA = [&](int tile, int h) {
    int tt = tile < nt ? tile : 0;
    u16* dst = ldsA(tile & 1, h);
    size_t row0 = (size_t)(m0 + h * 128);
#pragma unroll
    for (int i = 0; i < 2; ++i) {
      int e = i * 4096 + tid * 8;
      int r = e >> 6, s = (e >> 3) & 7;
      gl_lds16(A1 + (row0 + r) * (size_t)lda1 + tt * 64 + 8 * (s ^ (r & 7)), dst + e);
    }
  };
  auto stageB = [&](int tile, int h) {
    int tt = tile < nt ? tile : 0;
    u16* dst = ldsB(tile & 1, h);
    size_t row0 = (size_t)(n0 + h * 64);
    int e = tid * 8;
    int r = e >> 6, s = (e >> 3) & 7;
    gl_lds16(Bt + (row0 + r) * (size_t)K + tt * 64 + 8 * (s ^ (r & 7)), dst + e);
  };
  auto loadA = [&](bf16x8 (&a)[4][2], int buf, int qm) {
    const u16* src = ldsA(buf, qm);
#pragma unroll
    for (int mf = 0; mf < 4; ++mf) {
      int r = wm2 * 64 + mf * 16 + lo;
#pragma unroll
      for (int kk = 0; kk < 2; ++kk)
        a[mf][kk] = *(const bf16x8*)&src[r * 64 + (((kk * 4 + hi) ^ (r & 7)) << 3)];
    }
  };
  auto loadB = [&](bf16x8 (&bq)[2], int buf, int qn) {
    const u16* src = ldsB(buf, qn);
    int r = wn4 * 16 + lo;
#pragma unroll
    for (int kk = 0; kk < 2; ++kk)
      bq[kk] = *(const bf16x8*)&src[r * 64 + (((kk * 4 + hi) ^ (r & 7)) << 3)];
  };

  f32x4 acc00[4] = {}, acc01[4] = {}, acc10[4] = {}, acc11[4] = {};
  bf16x8 a_A[4][2], a_B[4][2], b0[2], b1[2];

  auto mma8 = [&](f32x4 (&accq)[4], bf16x8 (&aa)[4][2], bf16x8 (&bb)[2]) {
    __builtin_amdgcn_s_setprio(1);
#pragma unroll
    for (int kk = 0; kk < 2; ++kk)
#pragma unroll
      for (int mf = 0; mf < 4; ++mf)
        accq[mf] = __builtin_amdgcn_mfma_f32_16x16x32_bf16(aa[mf][kk], bb[kk], accq[mf], 0, 0, 0);
    __builtin_amdgcn_s_setprio(0);
  };

  // prologue: 12 stage loads; gate first 4 (A0h0 x2, B0h0, B0h1); issue q00 frags
  stageA(0, 0); stageB(0, 0); stageB(0, 1); stageA(0, 1);
  stageA(1, 0); stageB(1, 0); stageB(1, 1); stageA(1, 1);
  VMC(8); BAR;
  loadA(a_A, 0, 0);
  loadB(b0, 0, 0);
  FENCE;

  for (int it = 0; it < niter; ++it) {
    int t0 = 2 * it;
    // P1
    loadB(b1, 0, 1);
    LGKM(2); SGB;
    mma8(acc00, a_A, b0);
    VMC(6); BAR;
    // P2
    loadA(a_B, 0, 1);
    stageA(t0 + 2, 0);
    LGKM(8); SGB;
    mma8(acc01, a_A, b1);
    BAR;
    // P3
    stageB(t0 + 2, 0);
    LGKM(0); SGB;
    mma8(acc11, a_B, b1);
    VMC(6); BAR;
    // P4
    loadA(a_A, 1, 0);
    stageB(t0 + 2, 1);
    SGB;
    mma8(acc10, a_B, b0);
    loadB(b0, 1, 0);
    VMC(4); BAR;
    // P5
    loadB(b1, 1, 1);
    stageA(t0 + 2, 1);
    LGKM(2); SGB;
    mma8(acc00, a_A, b0);
    BAR;
    // P6
    loadA(a_B, 1, 1);
    stageA(t0 + 3, 0);
    LGKM(8); SGB;
    mma8(acc01, a_A, b1);
    BAR;
    // P7
    stageB(t0 + 3, 0);
    LGKM(0); SGB;
    mma8(acc11, a_B, b1);
    VMC(6); BAR;
    // P8
    loadA(a_A, 0, 0);
    stageB(t0 + 3, 1); stageA(t0 + 3, 1);
    SGB;
    mma8(acc10, a_B, b0);
    loadB(b0, 0, 0);
    VMC(8); BAR;
  }

  auto epi = [&](f32x4 (&accq)[4], int qm, int qn) {
    int col = n0 + qn * 64 + wn4 * 16 + lo;
    float bb = bias[col];
#pragma unroll
    for (int mf = 0; mf < 4; ++mf) {
      int row = m0 + qm * 128 + wm2 * 64 + mf * 16 + hi * 4;
      const float* rsd = nullptr; int roff = 0;
      if (resid0) { if (row < Msplit) { rsd = resid0; } else { rsd = resid1; roff = Msplit; } }
#pragma unroll
      for (int i = 0; i < 4; ++i) {
        float v = accq[mf][i] + bb;
        if (rsd) v += rsd[(size_t)(row + i - roff) * ldc + col];
        if (OUT_BF16) ((u16*)out)[(size_t)(row + i) * ldc + col] = f2bf(v);
        else          ((float*)out)[(size_t)(row + i) * ldc + col] = v;
      }
    }
  };
  epi(acc00, 0, 0); epi(acc01, 0, 1); epi(acc11, 1, 1); epi(acc10, 1, 0);
}

// ---------------- flash attention: 8 waves x 32q, 32x32x16 MFMA, P in-register ----------------
__global__ __launch_bounds__(512, 2) void k_attn(const u16* __restrict__ qkv,
                                                 const u16* __restrict__ vt01,
                                                 u16* __restrict__ m01) {
  __shared__ __align__(16) u16 q_lds[256 * 64];
  __shared__ __align__(16) u16 k_lds[2][64 * 64];
  __shared__ __align__(16) u16 v_lds[2][64 * 64];
  int z = blockIdx.z;
  const u16* Q  = qkv + (size_t)z * Mc * 2048;
  const u16* Kg = qkv + (size_t)(1 - z) * Mc * 2048;
  const u16* Vt = vt01 + (size_t)(1 - z) * VT_STRIDE;
  u16* Out = m01 + (size_t)z * Mc * Dc;
  int tid = threadIdx.x;
  int w = tid >> 6, l = tid & 63;
  int q31 = l & 31, h = l >> 5;
  int qt = blockIdx.x;
  int bh = blockIdx.y, b = bh >> 4, hd = bh & 15;
  size_t rowQ0 = (size_t)b * Nc + qt * 256;

  {
    int r = tid >> 3, s = tid & 7;
#pragma unroll
    for (int c = 0; c < 4; ++c)
      gl_lds16(Q + (rowQ0 + c * 64 + r) * 2048 + hd * 64 + 8 * SW(r, s),
               &q_lds[(size_t)(c * 512 + tid) * 8]);
    gl_lds16(Kg + ((size_t)b * Nc + r) * 2048 + hd * 64 + 8 * SW(r, s), &k_lds[0][(size_t)tid * 8]);
    gl_lds16(Vt + ((size_t)bh * 64 + r) * Nc + 8 * SW(r, s), &v_lds[0][(size_t)tid * 8]);
  }
  __syncthreads();

  bf16x8 qf[4];
  {
    int row = w * 32 + q31;
#pragma unroll
    for (int dk = 0; dk < 4; ++dk)
      qf[dk] = *(const bf16x8*)&q_lds[row * 64 + (SW(row, dk * 2 + h) << 3)];
  }

  f32x16 o0 = {}, o1 = {};
  float ls = 0.f;
  int cur = 0;

  for (int t = 0; t < Nc / 64; ++t) {
    if (t + 1 < Nc / 64) {
      int r = tid >> 3, s = tid & 7;
      gl_lds16(Kg + ((size_t)b * Nc + (t + 1) * 64 + r) * 2048 + hd * 64 + 8 * SW(r, s),
               &k_lds[cur ^ 1][(size_t)tid * 8]);
      gl_lds16(Vt + ((size_t)bh * 64 + r) * Nc + (t + 1) * 64 + 8 * SW(r, s),
               &v_lds[cur ^ 1][(size_t)tid * 8]);
    }

    f32x16 s0 = {}, s1 = {};
    __builtin_amdgcn_s_setprio(1);
#pragma unroll
    for (int dk = 0; dk < 4; ++dk) {
      int r0 = q31, r1 = 32 + q31;
      bf16x8 k0 = *(const bf16x8*)&k_lds[cur][r0 * 64 + (SW(r0, dk * 2 + h) << 3)];
      bf16x8 k1 = *(const bf16x8*)&k_lds[cur][r1 * 64 + (SW(r1, dk * 2 + h) << 3)];
      s0 = __builtin_amdgcn_mfma_f32_32x32x16_bf16(k0, qf[dk], s0, 0, 0, 0);
      s1 = __builtin_amdgcn_mfma_f32_32x32x16_bf16(k1, qf[dk], s1, 0, 0, 0);
    }
    __builtin_amdgcn_s_setprio(0);

    // softmax without max subtraction: p = exp2(s); sum via log-depth tree + permlane
    {
      float c16[16];
#pragma unroll
      for (int i = 0; i < 16; ++i) {
        float p0 = exp2f(s0[i]);
        float p1 = exp2f(s1[i]);
        s0[i] = p0; s1[i] = p1;
        c16[i] = p0 + p1;
      }
#pragma unroll
      for (int st = 8; st >= 1; st >>= 1)
#pragma unroll
        for (int i = 0; i < st; ++i) c16[i] += c16[i + st];
      u32 xa = __builtin_bit_cast(u32, c16[0]), xb = xa;
      asm("v_permlane32_swap_b32 %0, %1" : "+v"(xa), "+v"(xb));
      ls += __builtin_bit_cast(float, xa) + __builtin_bit_cast(float, xb);
    }

    u32 pk0[4][2], pk1[4][2];
#pragma unroll
    for (int a2 = 0; a2 < 4; ++a2)
#pragma unroll
      for (int c2 = 0; c2 < 2; ++c2) {
        asm("v_cvt_pk_bf16_f32 %0, %1, %2" : "=v"(pk0[a2][c2]) : "v"(s0[4 * a2 + 2 * c2]), "v"(s0[4 * a2 + 2 * c2 + 1]));
        asm("v_cvt_pk_bf16_f32 %0, %1, %2" : "=v"(pk1[a2][c2]) : "v"(s1[4 * a2 + 2 * c2]), "v"(s1[4 * a2 + 2 * c2 + 1]));
      }
    bf16x8 pf[4];
#pragma unroll
    for (int ks = 0; ks < 4; ++ks) {
      const int aE = (2 * ks) & 3, aO = (2 * ks + 1) & 3;
      u32 x0, y0, x1, y1;
      if (ks < 2) { x0 = pk0[aE][0]; y0 = pk0[aO][0]; x1 = pk0[aE][1]; y1 = pk0[aO][1]; }
      else        { x0 = pk1[aE][0]; y0 = pk1[aO][0]; x1 = pk1[aE][1]; y1 = pk1[aO][1]; }
      asm("v_permlane32_swap_b32 %0, %1" : "+v"(x0), "+v"(y0));
      asm("v_permlane32_swap_b32 %0, %1" : "+v"(x1), "+v"(y1));
      union { u32 u[4]; bf16x8 v; } fu;
      fu.u[0] = x0; fu.u[1] = x1; fu.u[2] = y0; fu.u[3] = y1;
      pf[ks] = fu.v;
    }

    __builtin_amdgcn_s_setprio(1);
#pragma unroll
    for (int ks = 0; ks < 4; ++ks) {
      int r0 = q31, r1 = 32 + q31;
      bf16x8 v0 = *(const bf16x8*)&v_lds[cur][r0 * 64 + (SW(r0, ks * 2 + h) << 3)];
      bf16x8 v1 = *(const bf16x8*)&v_lds[cur][r1 * 64 + (SW(r1, ks * 2 + h) << 3)];
      o0 = __builtin_amdgcn_mfma_f32_32x32x16_bf16(v0, pf[ks], o0, 0, 0, 0);
      o1 = __builtin_amdgcn_mfma_f32_32x32x16_bf16(v1, pf[ks], o1, 0, 0, 0);
    }
    __builtin_amdgcn_s_setprio(0);

    __syncthreads();
    cur ^= 1;
  }

  float inv = 1.f / ls;
  int q_abs = qt * 256 + w * 32 + q31;
  u16* orow = Out + ((size_t)b * Nc + q_abs) * Dc + hd * 64;
#pragma unroll
  for (int rq = 0; rq < 4; ++rq) {
    union { u16 s[4]; uint2 v; } p0, p1;
#pragma unroll
    for (int c = 0; c < 4; ++c) {
      p0.s[c] = f2bf(o0[4 * rq + c] * inv);
      p1.s[c] = f2bf(o1[4 * rq + c] * inv);
    }
    *(uint2*)(orow + 8 * rq + 4 * h) = p0.v;
    *(uint2*)(orow + 32 + 8 * rq + 4 * h) = p1.v;
  }
}

// ---------------- LayerNorm + exact-class GeLU: one row per WAVE ----------------
__global__ __launch_bounds__(256) void k_ln_gelu(u16* __restrict__ hbuf,
                                                 const float* __restrict__ gamma,
                                                 const float* __restrict__ beta) {
  int w = threadIdx.x >> 6, l = threadIdx.x & 63;
  int row = blockIdx.x * 4 + w;
  u16* hp = hbuf + (size_t)row * D2c;

  uint4 raw[4];
#pragma unroll
  for (int i = 0; i < 4; ++i)
    raw[i] = *(const uint4*)(hp + (i * 64 + l) * 8);

  float vals[32];
  float s = 0.f, s2 = 0.f;
#pragma unroll
  for (int i = 0; i < 4; ++i) {
    const u16* rs = (const u16*)&raw[i];
#pragma unroll
    for (int j = 0; j < 8; ++j) {
      float v = bf2f(rs[j]);
      vals[i * 8 + j] = v;
      s += v; s2 += v * v;
    }
  }
#pragma unroll
  for (int off = 1; off < 64; off <<= 1) {
    s += __shfl_xor(s, off);
    s2 += __shfl_xor(s2, off);
  }
  float mu = s * (1.f / D2c);
  float var = s2 * (1.f / D2c) - mu * mu;
  float rstd = rsqrtf(var + 1e-5f);

#pragma unroll
  for (int i = 0; i < 4; ++i) {
    int cbase = (i * 64 + l) * 8;
    float4 g0 = *(const float4*)(gamma + cbase);
    float4 g1 = *(const float4*)(gamma + cbase + 4);
    float4 b0 = *(const float4*)(beta + cbase);
    float4 b1 = *(const float4*)(beta + cbase + 4);
    float g[8] = {g0.x, g0.y, g0.z, g0.w, g1.x, g1.y, g1.z, g1.w};
    float bt[8] = {b0.x, b0.y, b0.z, b0.w, b1.x, b1.y, b1.z, b1.w};
    union { u16 s[8]; uint4 v; } o;
#pragma unroll
    for (int j = 0; j < 8; ++j) {
      float v = (vals[i * 8 + j] - mu) * rstd * g[j] + bt[j];
      o.s[j] = f2bf(gelu_exact(v));
    }
    *(uint4*)(hp + cbase) = o.v;
  }
}

extern "C" void kernel_launch(void* const* d_in, const int* in_sizes, int n_in,
                              void* d_out, int out_size, void* d_ws, size_t ws_size,
                              hipStream_t stream) {
  const float* x0   = (const float*)d_in[0];
  const float* x1   = (const float*)d_in[1];
  const float* Wqk  = (const float*)d_in[2];
  const float* bqk  = (const float*)d_in[3];
  const float* Wv   = (const float*)d_in[4];
  const float* bv   = (const float*)d_in[5];
  const float* Wo   = (const float*)d_in[6];
  const float* bo   = (const float*)d_in[7];
  const float* Wf1  = (const float*)d_in[8];
  const float* bf1  = (const float*)d_in[9];
  const float* gamma= (const float*)d_in[10];
  const float* beta = (const float*)d_in[11];
  const float* Wf2  = (const float*)d_in[12];
  const float* bf2  = (const float*)d_in[13];
  float* y = (float*)d_out;

  char* p = (char*)d_ws;
  auto take = [&](size_t elems) { u16* r = (u16*)p; p += ((elems * 2 + 255) & ~(size_t)255); return r; };
  u16* Wqkvt = take((size_t)2048 * 1024);   // rows 0..1023 = Wqk^T, 1024..2047 = Wv^T
  u16* Wot   = take((size_t)1024 * 1024);
  u16* Wf1t  = take((size_t)2048 * 2048);
  u16* Wf2t  = take((size_t)2048 * 1024);
  u16* x01b  = take((size_t)8192 * 1024);
  u16* qkv   = take((size_t)8192 * 2048);   // later aliased as h01
  u16* vt01  = take(2 * VT_STRIDE);         // later aliased as o01
  u16* m01   = take((size_t)8192 * 1024);
  u16* h01 = qkv;   // FFN1 output (qkv dead after attention)
  u16* o01 = vt01;  // O-proj output (vt dead after attention)

  dim3 blk(256);
  // sqrt(log2(e)/8): applied to both q and k -> S is scaled by log2(e)/8 (exp2-domain softmax)
  const float sq = 0.4246608984f;

  // weight transposes + input converts
  k_transpose_f32_bf16<<<dim3(16, 16), blk, 0, stream>>>(Wqk, Wqkvt, 1024, 1024);
  k_transpose_f32_bf16<<<dim3(16, 16), blk, 0, stream>>>(Wv, Wqkvt + (size_t)1024 * 1024, 1024, 1024);
  k_transpose_f32_bf16<<<dim3(16, 16), blk, 0, stream>>>(Wo, Wot, 1024, 1024);
  k_transpose_f32_bf16<<<dim3(32, 32), blk, 0, stream>>>(Wf1, Wf1t, 2048, 2048);
  k_transpose_f32_bf16<<<dim3(16, 32), blk, 0, stream>>>(Wf2, Wf2t, 2048, 1024);
  k_f32_to_bf16<<<dim3(2048), blk, 0, stream>>>(x0, x01b, 4096 * 1024);
  k_f32_to_bf16<<<dim3(2048), blk, 0, stream>>>(x1, x01b + (size_t)4096 * 1024, 4096 * 1024);

  // fused qk+v projection (pipelined 256^2): [8192,1024] x [1024,2048] -> qkv
  k_gemm8<<<dim3(256), dim3(512), 0, stream>>>(
      x01b, 1024, x01b, 1024, 16, Wqkvt,
      bqk, bv, 1024, sq, 1.f, qkv, 2048, 1024, 8);

  // per-head V transpose (both streams)
  k_v_transpose<<<dim3(16, 64, 2), blk, 0, stream>>>(qkv, vt01);

  // cross attention (both directions in one dispatch)
  k_attn<<<dim3(4, 64, 2), dim3(512), 0, stream>>>(qkv, vt01, m01);

  // output projection (pipelined 256x128): [8192,1024] x [1024,1024] -> o01
  k_gemm8h<true><<<dim3(256), dim3(512), 0, stream>>>(
      m01, 1024, Wot, bo, nullptr, nullptr, 0, o01, 1024, 1024, 8);

  // FFN1 on concat([x, o]) (pipelined 256^2): [8192,2048] x [2048,2048] -> h01
  k_gemm8<<<dim3(256), dim3(512), 0, stream>>>(
      x01b, 1024, o01, 1024, 16, Wf1t,
      bf1, nullptr, 2048, 1.f, 1.f, h01, 2048, 2048, 8);

  // LayerNorm + GeLU in place (one row per wave)
  k_ln_gelu<<<dim3(2048), blk, 0, stream>>>(h01, gamma, beta);

  // FFN2 + residual (pipelined 256x128) -> fp32 outputs
  k_gemm8h<false><<<dim3(256), dim3(512), 0, stream>>>(
      h01, 2048, Wf2t, bf2, x0, x1, 4096, y, 1024, 2048, 8);
}

// Round 13
// 280.786 us; speedup vs baseline: 1.2349x; 1.2349x over previous
//
#include <hip/hip_runtime.h>
#include <hip/hip_bf16.h>

typedef unsigned short u16;
typedef unsigned int u32;
typedef __attribute__((ext_vector_type(8))) short bf16x8;
typedef __attribute__((ext_vector_type(4))) float f32x4;
typedef __attribute__((ext_vector_type(16))) float f32x16;

#define DEV __device__ __forceinline__
#define FENCE asm volatile("" ::: "memory")
#define WAITL asm volatile("s_waitcnt lgkmcnt(0)" ::: "memory")
#define BAR __builtin_amdgcn_s_barrier()
#define VMC(n) asm volatile("s_waitcnt vmcnt(" #n ")" ::: "memory")

static constexpr int Bc = 4, Nc = 1024, Dc = 1024, Hc = 16, Mc = 4096, D2c = 2048;
static constexpr size_t VT_STRIDE = (size_t)4 * 16 * 64 * 1024;  // per-stream vt elems

DEV u16 f2bf(float f) {
  u32 u = __builtin_bit_cast(u32, f);
  u = (u + 0x7FFFu + ((u >> 16) & 1u)) >> 16;
  return (u16)u;
}
DEV float bf2f(u16 h) { u32 u = ((u32)h) << 16; return __builtin_bit_cast(float, u); }
DEV void gl_lds16(const void* g, void* l) {
  __builtin_amdgcn_global_load_lds((const __attribute__((address_space(1))) u32*)g,
                                   (__attribute__((address_space(3))) u32*)l, 16, 0, 0);
}
// deep swizzle for k_attn: separates rows 8 apart (row-stride 128B == bank cycle)
DEV int SW(int r, int c) { return c ^ (r & 7) ^ ((r >> 3) & 3); }

// exact-class erf: Abramowitz-Stegun 7.1.26, |err| < 1.5e-7
DEV float erf_fast(float x) {
  float ax = __builtin_fabsf(x);
  float t = __builtin_amdgcn_rcpf(__builtin_fmaf(0.3275911f, ax, 1.0f));
  float p = __builtin_fmaf(1.061405429f, t, -1.453152027f);
  p = __builtin_fmaf(p, t, 1.421413741f);
  p = __builtin_fmaf(p, t, -0.284496736f);
  p = __builtin_fmaf(p, t, 0.254829592f);
  p *= t;
  float e = __builtin_amdgcn_exp2f(-1.4426950408889634f * ax * ax);  // exp(-x^2)
  float r = __builtin_fmaf(-p, e, 1.0f);
  return __builtin_copysignf(r, x);
}
DEV float gelu_exact(float v) {
  return 0.5f * v * (1.0f + erf_fast(v * 0.70710678118654752f));
}

// ---------------- fp32 -> bf16 convert (vectorized) ----------------
__global__ __launch_bounds__(256) void k_f32_to_bf16(const float* __restrict__ in,
                                                     u16* __restrict__ out, int n) {
  int i = (blockIdx.x * 256 + threadIdx.x) * 8;
  if (i >= n) return;
  float4 a = *(const float4*)(in + i);
  float4 b = *(const float4*)(in + i + 4);
  union { u16 s[8]; uint4 v; } r;
  r.s[0] = f2bf(a.x); r.s[1] = f2bf(a.y); r.s[2] = f2bf(a.z); r.s[3] = f2bf(a.w);
  r.s[4] = f2bf(b.x); r.s[5] = f2bf(b.y); r.s[6] = f2bf(b.z); r.s[7] = f2bf(b.w);
  *(uint4*)(out + i) = r.v;
}

// ---------------- fp32 [R][C] -> bf16 [C][R] transpose-convert ----------------
__global__ __launch_bounds__(256) void k_transpose_f32_bf16(const float* __restrict__ in,
                                                            u16* __restrict__ out, int R, int C) {
  __shared__ float t[64][65];
  int c0 = blockIdx.x * 64, r0 = blockIdx.y * 64;
  int tid = threadIdx.x;
  int rr = tid >> 4, cc4 = (tid & 15) * 4;
  for (int k = 0; k < 4; ++k) {
    int r = rr + k * 16;
    float4 v = *(const float4*)(in + (size_t)(r0 + r) * C + c0 + cc4);
    t[r][cc4 + 0] = v.x; t[r][cc4 + 1] = v.y; t[r][cc4 + 2] = v.z; t[r][cc4 + 3] = v.w;
  }
  __syncthreads();
  int cw = tid >> 4, rr4 = (tid & 15) * 4;
  for (int k = 0; k < 4; ++k) {
    int c = cw + k * 16;
    union { u16 s[4]; uint2 v; } p;
    for (int j = 0; j < 4; ++j) p.s[j] = f2bf(t[rr4 + j][c]);
    *(uint2*)(out + (size_t)(c0 + c) * R + r0 + rr4) = p.v;
  }
}

// ---------------- 256x256x64 8-phase GEMM, deep-prefetch counted-vmcnt schedule ----------------
// (round-11 proven structure). Optional vt_out: columns >= Nsplit are written
// transposed per-head into vt (4 consecutive rows -> one uint2), fusing k_v_transpose.
__global__ __launch_bounds__(512, 1) void k_gemm8(
    const u16* __restrict__ A1, int lda1, const u16* __restrict__ A2, int lda2, int kstile,
    const u16* __restrict__ Bt, const float* __restrict__ bias1, const float* __restrict__ bias2,
    int Nsplit, float scale1, float scale2, u16* __restrict__ out, int ldc, int K, int gx,
    u16* __restrict__ vt_out) {
  __shared__ __align__(16) u16 lds[65536];  // [A|B][buf][half][128*64]
  int tid = threadIdx.x;
  int w = tid >> 6, l = tid & 63;
  int lo = l & 15, hi = l >> 4;
  int wm2 = w >> 2, wn4 = w & 3;
  int nt = K >> 6, niter = nt >> 1;

  int nwg = gridDim.x;
  int swz = (blockIdx.x & 7) * (nwg >> 3) + (blockIdx.x >> 3);
  int m0 = (swz / gx) * 256, n0 = (swz % gx) * 256;

  auto ldsA = [&](int buf, int h) -> u16* { return lds + ((buf << 1) + h) * 8192; };
  auto ldsB = [&](int buf, int h) -> u16* { return lds + 32768 + ((buf << 1) + h) * 8192; };

  auto stageA = [&](int tile, int h) {
    int tt = tile < nt ? tile : 0;
    const u16* base; int ldx, kof;
    if (tt < kstile) { base = A1; ldx = lda1; kof = tt * 64; }
    else             { base = A2; ldx = lda2; kof = (tt - kstile) * 64; }
    u16* dst = ldsA(tile & 1, h);
    size_t row0 = (size_t)(m0 + h * 128);
#pragma unroll
    for (int i = 0; i < 2; ++i) {
      int e = i * 4096 + tid * 8;
      int r = e >> 6, s = (e >> 3) & 7;
      gl_lds16(base + (row0 + r) * (size_t)ldx + kof + 8 * (s ^ (r & 7)), dst + e);
    }
  };
  auto stageB = [&](int tile, int h) {
    int tt = tile < nt ? tile : 0;
    u16* dst = ldsB(tile & 1, h);
    size_t row0 = (size_t)(n0 + h * 128);
#pragma unroll
    for (int i = 0; i < 2; ++i) {
      int e = i * 4096 + tid * 8;
      int r = e >> 6, s = (e >> 3) & 7;
      gl_lds16(Bt + (row0 + r) * (size_t)K + tt * 64 + 8 * (s ^ (r & 7)), dst + e);
    }
  };
  auto loadA = [&](bf16x8 (&a)[4][2], int buf, int qm) {
    const u16* src = ldsA(buf, qm);
#pragma unroll
    for (int mf = 0; mf < 4; ++mf) {
      int r = wm2 * 64 + mf * 16 + lo;
#pragma unroll
      for (int kk = 0; kk < 2; ++kk)
        a[mf][kk] = *(const bf16x8*)&src[r * 64 + (((kk * 4 + hi) ^ (r & 7)) << 3)];
    }
  };
  auto loadB = [&](bf16x8 (&bq)[2][2], int buf, int qn) {
    const u16* src = ldsB(buf, qn);
#pragma unroll
    for (int nf = 0; nf < 2; ++nf) {
      int r = wn4 * 32 + nf * 16 + lo;
#pragma unroll
      for (int kk = 0; kk < 2; ++kk)
        bq[nf][kk] = *(const bf16x8*)&src[r * 64 + (((kk * 4 + hi) ^ (r & 7)) << 3)];
    }
  };

  f32x4 acc00[4][2] = {}, acc01[4][2] = {}, acc10[4][2] = {}, acc11[4][2] = {};
  bf16x8 a[4][2], b0[2][2], b1[2][2];

  auto mmaQ = [&](f32x4 (&accq)[4][2], bf16x8 (&aa)[4][2], bf16x8 (&bb)[2][2]) {
    __builtin_amdgcn_s_setprio(1);
#pragma unroll
    for (int mf = 0; mf < 4; ++mf)
#pragma unroll
      for (int nf = 0; nf < 2; ++nf)
#pragma unroll
        for (int kk = 0; kk < 2; ++kk)
          accq[mf][nf] = __builtin_amdgcn_mfma_f32_16x16x32_bf16(aa[mf][kk], bb[nf][kk], accq[mf][nf], 0, 0, 0);
    __builtin_amdgcn_s_setprio(0);
  };

  // prologue = virtual previous iteration's stage order
  stageA(0, 0); stageB(0, 0); stageB(0, 1); stageA(0, 1);
  stageA(1, 0); stageB(1, 0); stageB(1, 1); stageA(1, 1);
  VMC(12); BAR;

  for (int it = 0; it < niter; ++it) {
    int t0 = 2 * it;
    // PH1: buf0 A.h0, B.h0
    loadA(a, 0, 0); loadB(b0, 0, 0);
    FENCE; BAR; WAITL;
    mmaQ(acc00, a, b0);
    FENCE; VMC(10); BAR;
    // PH2: buf0 B.h1 ; stage A(t+2,0)
    loadB(b1, 0, 1);
    stageA(t0 + 2, 0);
    FENCE; BAR; WAITL;
    mmaQ(acc01, a, b1);
    FENCE; VMC(10); BAR;
    // PH3: buf0 A.h1 ; stage B(t+2,0)
    loadA(a, 0, 1);
    stageB(t0 + 2, 0);
    FENCE; BAR; WAITL;
    mmaQ(acc10, a, b0);
    FENCE; BAR;
    // PH4: regs ; stage B(t+2,1)
    stageB(t0 + 2, 1);
    FENCE; BAR;
    mmaQ(acc11, a, b1);
    FENCE; VMC(10); BAR;
    // PH5: buf1 A.h0, B.h0 ; stage A(t+2,1)
    loadA(a, 1, 0); loadB(b0, 1, 0);
    stageA(t0 + 2, 1);
    FENCE; BAR; WAITL;
    mmaQ(acc00, a, b0);
    FENCE; VMC(10); BAR;
    // PH6: buf1 B.h1 ; stage A(t+3,0)
    loadB(b1, 1, 1);
    stageA(t0 + 3, 0);
    FENCE; BAR; WAITL;
    mmaQ(acc01, a, b1);
    FENCE; VMC(10); BAR;
    // PH7: buf1 A.h1 ; stage B(t+3,0)
    loadA(a, 1, 1);
    stageB(t0 + 3, 0);
    FENCE; BAR; WAITL;
    mmaQ(acc10, a, b0);
    FENCE; BAR;
    // PH8: regs ; stage B(t+3,1), A(t+3,1)
    stageB(t0 + 3, 1); stageA(t0 + 3, 1);
    FENCE; BAR;
    mmaQ(acc11, a, b1);
    FENCE; VMC(12); BAR;
  }

  auto epi = [&](f32x4 (&accq)[4][2], int qm, int qn) {
#pragma unroll
    for (int mf = 0; mf < 4; ++mf)
#pragma unroll
      for (int nf = 0; nf < 2; ++nf) {
        int col = n0 + qn * 128 + wn4 * 32 + nf * 16 + lo;
        float bb, sc;
        if (col < Nsplit) { bb = bias1[col]; sc = scale1; }
        else              { bb = bias2[col - Nsplit]; sc = scale2; }
        int row = m0 + qm * 128 + wm2 * 64 + mf * 16 + hi * 4;
        if (vt_out && col >= Nsplit) {
          // fused per-head V transpose: 4 consecutive rows = 4 consecutive n
          int dg = col - Nsplit;
          int z = row >> 12;
          int b = (row >> 10) & 3, n = row & 1023;
          int bh = b * 16 + (dg >> 6), d = dg & 63;
          union { u16 s[4]; uint2 v; } pk;
#pragma unroll
          for (int i = 0; i < 4; ++i) pk.s[i] = f2bf((accq[mf][nf][i] + bb) * sc);
          *(uint2*)(vt_out + (size_t)z * VT_STRIDE + ((size_t)bh * 64 + d) * 1024 + n) = pk.v;
        } else {
#pragma unroll
          for (int i = 0; i < 4; ++i)
            out[(size_t)(row + i) * ldc + col] = f2bf((accq[mf][nf][i] + bb) * sc);
        }
      }
  };
  epi(acc00, 0, 0); epi(acc01, 0, 1); epi(acc10, 1, 0); epi(acc11, 1, 1);
}

// ---------------- 256x128x64 8-phase GEMM variant (round-11 proven structure) ----------------
template <bool OUT_BF16>
__global__ __launch_bounds__(512, 1) void k_gemm8h(
    const u16* __restrict__ A1, int lda1, const u16* __restrict__ Bt,
    const float* __restrict__ bias,
    const float* __restrict__ resid0, const float* __restrict__ resid1, int Msplit,
    void* __restrict__ out, int ldc, int K, int gx) {
  __shared__ __align__(16) u16 lds[49152];  // A: 2buf*2half*8192, B: 2buf*2half*4096
  int tid = threadIdx.x;
  int w = tid >> 6, l = tid & 63;
  int lo = l & 15, hi = l >> 4;
  int wm2 = w >> 2, wn4 = w & 3;
  int nt = K >> 6, niter = nt >> 1;

  int nwg = gridDim.x;
  int swz = (blockIdx.x & 7) * (nwg >> 3) + (blockIdx.x >> 3);
  int m0 = (swz / gx) * 256, n0 = (swz % gx) * 128;

  auto ldsA = [&](int buf, int h) -> u16* { return lds + ((buf << 1) + h) * 8192; };
  auto ldsB = [&](int buf, int h) -> u16* { return lds + 32768 + ((buf << 1) + h) * 4096; };

  auto stageA = [&](int tile, int h) {
    int tt = tile < nt ? tile : 0;
    u16* dst = ldsA(tile & 1, h);
    size_t row0 = (size_t)(m0 + h * 128);
#pragma unroll
    for (int i = 0; i < 2; ++i) {
      int e = i * 4096 + tid * 8;
      int r = e >> 6, s = (e >> 3) & 7;
      gl_lds16(A1 + (row0 + r) * (size_t)lda1 + tt * 64 + 8 * (s ^ (r & 7)), dst + e);
    }
  };
  auto stageB = [&](int tile, int h) {
    int tt = tile < nt ? tile : 0;
    u16* dst = ldsB(tile & 1, h);
    size_t row0 = (size_t)(n0 + h * 64);
    int e = tid * 8;
    int r = e >> 6, s = (e >> 3) & 7;
    gl_lds16(Bt + (row0 + r) * (size_t)K + tt * 64 + 8 * (s ^ (r & 7)), dst + e);
  };
  auto loadA = [&](bf16x8 (&a)[4][2], int buf, int qm) {
    const u16* src = ldsA(buf, qm);
#pragma unroll
    for (int mf = 0; mf < 4; ++mf) {
      int r = wm2 * 64 + mf * 16 + lo;
#pragma unroll
      for (int kk = 0; kk < 2; ++kk)
        a[mf][kk] = *(const bf16x8*)&src[r * 64 + (((kk * 4 + hi) ^ (r & 7)) << 3)];
    }
  };
  auto loadB = [&](bf16x8 (&bq)[2], int buf, int qn) {
    const u16* src = ldsB(buf, qn);
    int r = wn4 * 16 + lo;
#pragma unroll
    for (int kk = 0; kk < 2; ++kk)
      bq[kk] = *(const bf16x8*)&src[r * 64 + (((kk * 4 + hi) ^ (r & 7)) << 3)];
  };

  f32x4 acc00[4] = {}, acc01[4] = {}, acc10[4] = {}, acc11[4] = {};
  bf16x8 a[4][2], b0[2], b1[2];

  auto mma8 = [&](f32x4 (&accq)[4], bf16x8 (&aa)[4][2], bf16x8 (&bb)[2]) {
    __builtin_amdgcn_s_setprio(1);
#pragma unroll
    for (int mf = 0; mf < 4; ++mf)
#pragma unroll
      for (int kk = 0; kk < 2; ++kk)
        accq[mf] = __builtin_amdgcn_mfma_f32_16x16x32_bf16(aa[mf][kk], bb[kk], accq[mf], 0, 0, 0);
    __builtin_amdgcn_s_setprio(0);
  };

  // prologue = virtual previous iteration's stage order
  stageA(0, 0); stageB(0, 0); stageB(0, 1); stageA(0, 1);
  stageA(1, 0); stageB(1, 0); stageB(1, 1); stageA(1, 1);
  VMC(9); BAR;

  for (int it = 0; it < niter; ++it) {
    int t0 = 2 * it;
    // PH1
    loadA(a, 0, 0); loadB(b0, 0, 0);
    FENCE; BAR; WAITL;
    mma8(acc00, a, b0);
    FENCE; VMC(8); BAR;
    // PH2 ; stage A(t+2,0)
    loadB(b1, 0, 1);
    stageA(t0 + 2, 0);
    FENCE; BAR; WAITL;
    mma8(acc01, a, b1);
    FENCE; VMC(8); BAR;
    // PH3 ; stage B(t+2,0)
    loadA(a, 0, 1);
    stageB(t0 + 2, 0);
    FENCE; BAR; WAITL;
    mma8(acc10, a, b0);
    FENCE; BAR;
    // PH4 ; stage B(t+2,1)
    stageB(t0 + 2, 1);
    FENCE; BAR;
    mma8(acc11, a, b1);
    FENCE; VMC(7); BAR;
    // PH5 ; stage A(t+2,1)
    loadA(a, 1, 0); loadB(b0, 1, 0);
    stageA(t0 + 2, 1);
    FENCE; BAR; WAITL;
    mma8(acc00, a, b0);
    FENCE; VMC(8); BAR;
    // PH6 ; stage A(t+3,0)
    loadB(b1, 1, 1);
    stageA(t0 + 3, 0);
    FENCE; BAR; WAITL;
    mma8(acc01, a, b1);
    FENCE; VMC(8); BAR;
    // PH7 ; stage B(t+3,0)
    loadA(a, 1, 1);
    stageB(t0 + 3, 0);
    FENCE; BAR; WAITL;
    mma8(acc10, a, b0);
    FENCE; BAR;
    // PH8 ; stage B(t+3,1), A(t+3,1)
    stageB(t0 + 3, 1); stageA(t0 + 3, 1);
    FENCE; BAR;
    mma8(acc11, a, b1);
    FENCE; VMC(9); BAR;
  }

  auto epi = [&](f32x4 (&accq)[4], int qm, int qn) {
    int col = n0 + qn * 64 + wn4 * 16 + lo;
    float bb = bias[col];
#pragma unroll
    for (int mf = 0; mf < 4; ++mf) {
      int row = m0 + qm * 128 + wm2 * 64 + mf * 16 + hi * 4;
      const float* rsd = nullptr; int roff = 0;
      if (resid0) { if (row < Msplit) { rsd = resid0; } else { rsd = resid1; roff = Msplit; } }
#pragma unroll
      for (int i = 0; i < 4; ++i) {
        float v = accq[mf][i] + bb;
        if (rsd) v += rsd[(size_t)(row + i - roff) * ldc + col];
        if (OUT_BF16) ((u16*)out)[(size_t)(row + i) * ldc + col] = f2bf(v);
        else          ((float*)out)[(size_t)(row + i) * ldc + col] = v;
      }
    }
  };
  epi(acc00, 0, 0); epi(acc01, 0, 1); epi(acc10, 1, 0); epi(acc11, 1, 1);
}

// ---------------- flash attention: 8 waves x 32q, 32x32x16 MFMA, P in-register ----------------
__global__ __launch_bounds__(512, 2) void k_attn(const u16* __restrict__ qkv,
                                                 const u16* __restrict__ vt01,
                                                 u16* __restrict__ m01) {
  __shared__ __align__(16) u16 q_lds[256 * 64];
  __shared__ __align__(16) u16 k_lds[2][64 * 64];
  __shared__ __align__(16) u16 v_lds[2][64 * 64];
  int z = blockIdx.z;
  const u16* Q  = qkv + (size_t)z * Mc * 2048;
  const u16* Kg = qkv + (size_t)(1 - z) * Mc * 2048;
  const u16* Vt = vt01 + (size_t)(1 - z) * VT_STRIDE;
  u16* Out = m01 + (size_t)z * Mc * Dc;
  int tid = threadIdx.x;
  int w = tid >> 6, l = tid & 63;
  int q31 = l & 31, h = l >> 5;
  int qt = blockIdx.x;
  int bh = blockIdx.y, b = bh >> 4, hd = bh & 15;
  size_t rowQ0 = (size_t)b * Nc + qt * 256;

  {
    int r = tid >> 3, s = tid & 7;
#pragma unroll
    for (int c = 0; c < 4; ++c)
      gl_lds16(Q + (rowQ0 + c * 64 + r) * 2048 + hd * 64 + 8 * SW(r, s),
               &q_lds[(size_t)(c * 512 + tid) * 8]);
    gl_lds16(Kg + ((size_t)b * Nc + r) * 2048 + hd * 64 + 8 * SW(r, s), &k_lds[0][(size_t)tid * 8]);
    gl_lds16(Vt + ((size_t)bh * 64 + r) * Nc + 8 * SW(r, s), &v_lds[0][(size_t)tid * 8]);
  }
  __syncthreads();

  bf16x8 qf[4];
  {
    int row = w * 32 + q31;
#pragma unroll
    for (int dk = 0; dk < 4; ++dk)
      qf[dk] = *(const bf16x8*)&q_lds[row * 64 + (SW(row, dk * 2 + h) << 3)];
  }

  f32x16 o0 = {}, o1 = {};
  float ls = 0.f;
  int cur = 0;

  for (int t = 0; t < Nc / 64; ++t) {
    if (t + 1 < Nc / 64) {
      int r = tid >> 3, s = tid & 7;
      gl_lds16(Kg + ((size_t)b * Nc + (t + 1) * 64 + r) * 2048 + hd * 64 + 8 * SW(r, s),
               &k_lds[cur ^ 1][(size_t)tid * 8]);
      gl_lds16(Vt + ((size_t)bh * 64 + r) * Nc + (t + 1) * 64 + 8 * SW(r, s),
               &v_lds[cur ^ 1][(size_t)tid * 8]);
    }

    f32x16 s0 = {}, s1 = {};
    __builtin_amdgcn_s_setprio(1);
#pragma unroll
    for (int dk = 0; dk < 4; ++dk) {
      int r0 = q31, r1 = 32 + q31;
      bf16x8 k0 = *(const bf16x8*)&k_lds[cur][r0 * 64 + (SW(r0, dk * 2 + h) << 3)];
      bf16x8 k1 = *(const bf16x8*)&k_lds[cur][r1 * 64 + (SW(r1, dk * 2 + h) << 3)];
      s0 = __builtin_amdgcn_mfma_f32_32x32x16_bf16(k0, qf[dk], s0, 0, 0, 0);
      s1 = __builtin_amdgcn_mfma_f32_32x32x16_bf16(k1, qf[dk], s1, 0, 0, 0);
    }
    __builtin_amdgcn_s_setprio(0);

    // softmax without max subtraction: p = exp2(s); sum via log-depth tree + permlane
    {
      float c16[16];
#pragma unroll
      for (int i = 0; i < 16; ++i) {
        float p0 = exp2f(s0[i]);
        float p1 = exp2f(s1[i]);
        s0[i] = p0; s1[i] = p1;
        c16[i] = p0 + p1;
      }
#pragma unroll
      for (int st = 8; st >= 1; st >>= 1)
#pragma unroll
        for (int i = 0; i < st; ++i) c16[i] += c16[i + st];
      u32 xa = __builtin_bit_cast(u32, c16[0]), xb = xa;
      asm("v_permlane32_swap_b32 %0, %1" : "+v"(xa), "+v"(xb));
      ls += __builtin_bit_cast(float, xa) + __builtin_bit_cast(float, xb);
    }

    u32 pk0[4][2], pk1[4][2];
#pragma unroll
    for (int a2 = 0; a2 < 4; ++a2)
#pragma unroll
      for (int c2 = 0; c2 < 2; ++c2) {
        asm("v_cvt_pk_bf16_f32 %0, %1, %2" : "=v"(pk0[a2][c2]) : "v"(s0[4 * a2 + 2 * c2]), "v"(s0[4 * a2 + 2 * c2 + 1]));
        asm("v_cvt_pk_bf16_f32 %0, %1, %2" : "=v"(pk1[a2][c2]) : "v"(s1[4 * a2 + 2 * c2]), "v"(s1[4 * a2 + 2 * c2 + 1]));
      }
    bf16x8 pf[4];
#pragma unroll
    for (int ks = 0; ks < 4; ++ks) {
      const int aE = (2 * ks) & 3, aO = (2 * ks + 1) & 3;
      u32 x0, y0, x1, y1;
      if (ks < 2) { x0 = pk0[aE][0]; y0 = pk0[aO][0]; x1 = pk0[aE][1]; y1 = pk0[aO][1]; }
      else        { x0 = pk1[aE][0]; y0 = pk1[aO][0]; x1 = pk1[aE][1]; y1 = pk1[aO][1]; }
      asm("v_permlane32_swap_b32 %0, %1" : "+v"(x0), "+v"(y0));
      asm("v_permlane32_swap_b32 %0, %1" : "+v"(x1), "+v"(y1));
      union { u32 u[4]; bf16x8 v; } fu;
      fu.u[0] = x0; fu.u[1] = x1; fu.u[2] = y0; fu.u[3] = y1;
      pf[ks] = fu.v;
    }

    __builtin_amdgcn_s_setprio(1);
#pragma unroll
    for (int ks = 0; ks < 4; ++ks) {
      int r0 = q31, r1 = 32 + q31;
      bf16x8 v0 = *(const bf16x8*)&v_lds[cur][r0 * 64 + (SW(r0, ks * 2 + h) << 3)];
      bf16x8 v1 = *(const bf16x8*)&v_lds[cur][r1 * 64 + (SW(r1, ks * 2 + h) << 3)];
      o0 = __builtin_amdgcn_mfma_f32_32x32x16_bf16(v0, pf[ks], o0, 0, 0, 0);
      o1 = __builtin_amdgcn_mfma_f32_32x32x16_bf16(v1, pf[ks], o1, 0, 0, 0);
    }
    __builtin_amdgcn_s_setprio(0);

    __syncthreads();
    cur ^= 1;
  }

  float inv = 1.f / ls;
  int q_abs = qt * 256 + w * 32 + q31;
  u16* orow = Out + ((size_t)b * Nc + q_abs) * Dc + hd * 64;
#pragma unroll
  for (int rq = 0; rq < 4; ++rq) {
    union { u16 s[4]; uint2 v; } p0, p1;
#pragma unroll
    for (int c = 0; c < 4; ++c) {
      p0.s[c] = f2bf(o0[4 * rq + c] * inv);
      p1.s[c] = f2bf(o1[4 * rq + c] * inv);
    }
    *(uint2*)(orow + 8 * rq + 4 * h) = p0.v;
    *(uint2*)(orow + 32 + 8 * rq + 4 * h) = p1.v;
  }
}

// ---------------- LayerNorm + exact-class GeLU: one row per WAVE ----------------
__global__ __launch_bounds__(256) void k_ln_gelu(u16* __restrict__ hbuf,
                                                 const float* __restrict__ gamma,
                                                 const float* __restrict__ beta) {
  int w = threadIdx.x >> 6, l = threadIdx.x & 63;
  int row = blockIdx.x * 4 + w;
  u16* hp = hbuf + (size_t)row * D2c;

  uint4 raw[4];
#pragma unroll
  for (int i = 0; i < 4; ++i)
    raw[i] = *(const uint4*)(hp + (i * 64 + l) * 8);

  float vals[32];
  float s = 0.f, s2 = 0.f;
#pragma unroll
  for (int i = 0; i < 4; ++i) {
    const u16* rs = (const u16*)&raw[i];
#pragma unroll
    for (int j = 0; j < 8; ++j) {
      float v = bf2f(rs[j]);
      vals[i * 8 + j] = v;
      s += v; s2 += v * v;
    }
  }
#pragma unroll
  for (int off = 1; off < 64; off <<= 1) {
    s += __shfl_xor(s, off);
    s2 += __shfl_xor(s2, off);
  }
  float mu = s * (1.f / D2c);
  float var = s2 * (1.f / D2c) - mu * mu;
  float rstd = rsqrtf(var + 1e-5f);

#pragma unroll
  for (int i = 0; i < 4; ++i) {
    int cbase = (i * 64 + l) * 8;
    float4 g0 = *(const float4*)(gamma + cbase);
    float4 g1 = *(const float4*)(gamma + cbase + 4);
    float4 b0 = *(const float4*)(beta + cbase);
    float4 b1 = *(const float4*)(beta + cbase + 4);
    float g[8] = {g0.x, g0.y, g0.z, g0.w, g1.x, g1.y, g1.z, g1.w};
    float bt[8] = {b0.x, b0.y, b0.z, b0.w, b1.x, b1.y, b1.z, b1.w};
    union { u16 s[8]; uint4 v; } o;
#pragma unroll
    for (int j = 0; j < 8; ++j) {
      float v = (vals[i * 8 + j] - mu) * rstd * g[j] + bt[j];
      o.s[j] = f2bf(gelu_exact(v));
    }
    *(uint4*)(hp + cbase) = o.v;
  }
}

extern "C" void kernel_launch(void* const* d_in, const int* in_sizes, int n_in,
                              void* d_out, int out_size, void* d_ws, size_t ws_size,
                              hipStream_t stream) {
  const float* x0   = (const float*)d_in[0];
  const float* x1   = (const float*)d_in[1];
  const float* Wqk  = (const float*)d_in[2];
  const float* bqk  = (const float*)d_in[3];
  const float* Wv   = (const float*)d_in[4];
  const float* bv   = (const float*)d_in[5];
  const float* Wo   = (const float*)d_in[6];
  const float* bo   = (const float*)d_in[7];
  const float* Wf1  = (const float*)d_in[8];
  const float* bf1  = (const float*)d_in[9];
  const float* gamma= (const float*)d_in[10];
  const float* beta = (const float*)d_in[11];
  const float* Wf2  = (const float*)d_in[12];
  const float* bf2  = (const float*)d_in[13];
  float* y = (float*)d_out;

  char* p = (char*)d_ws;
  auto take = [&](size_t elems) { u16* r = (u16*)p; p += ((elems * 2 + 255) & ~(size_t)255); return r; };
  u16* Wqkvt = take((size_t)2048 * 1024);   // rows 0..1023 = Wqk^T, 1024..2047 = Wv^T
  u16* Wot   = take((size_t)1024 * 1024);
  u16* Wf1t  = take((size_t)2048 * 2048);
  u16* Wf2t  = take((size_t)2048 * 1024);
  u16* x01b  = take((size_t)8192 * 1024);
  u16* qkv   = take((size_t)8192 * 2048);   // later aliased as h01
  u16* vt01  = take(2 * VT_STRIDE);         // later aliased as o01
  u16* m01   = take((size_t)8192 * 1024);
  u16* h01 = qkv;   // FFN1 output (qkv dead after attention)
  u16* o01 = vt01;  // O-proj output (vt dead after attention)

  dim3 blk(256);
  // sqrt(log2(e)/8): applied to both q and k -> S is scaled by log2(e)/8 (exp2-domain softmax)
  const float sq = 0.4246608984f;

  // weight transposes + input converts
  k_transpose_f32_bf16<<<dim3(16, 16), blk, 0, stream>>>(Wqk, Wqkvt, 1024, 1024);
  k_transpose_f32_bf16<<<dim3(16, 16), blk, 0, stream>>>(Wv, Wqkvt + (size_t)1024 * 1024, 1024, 1024);
  k_transpose_f32_bf16<<<dim3(16, 16), blk, 0, stream>>>(Wo, Wot, 1024, 1024);
  k_transpose_f32_bf16<<<dim3(32, 32), blk, 0, stream>>>(Wf1, Wf1t, 2048, 2048);
  k_transpose_f32_bf16<<<dim3(16, 32), blk, 0, stream>>>(Wf2, Wf2t, 2048, 1024);
  k_f32_to_bf16<<<dim3(2048), blk, 0, stream>>>(x0, x01b, 4096 * 1024);
  k_f32_to_bf16<<<dim3(2048), blk, 0, stream>>>(x1, x01b + (size_t)4096 * 1024, 4096 * 1024);

  // fused qk+v projection (deep-prefetch 256^2) with fused per-head V transpose:
  // qk half -> qkv[.][0..1023]; v half -> vt01 directly (k_v_transpose eliminated)
  k_gemm8<<<dim3(256), dim3(512), 0, stream>>>(
      x01b, 1024, x01b, 1024, 16, Wqkvt,
      bqk, bv, 1024, sq, 1.f, qkv, 2048, 1024, 8, vt01);

  // cross attention (both directions in one dispatch)
  k_attn<<<dim3(4, 64, 2), dim3(512), 0, stream>>>(qkv, vt01, m01);

  // output projection (deep-prefetch 256x128): [8192,1024] x [1024,1024] -> o01
  k_gemm8h<true><<<dim3(256), dim3(512), 0, stream>>>(
      m01, 1024, Wot, bo, nullptr, nullptr, 0, o01, 1024, 1024, 8);

  // FFN1 on concat([x, o]) (deep-prefetch 256^2): [8192,2048] x [2048,2048] -> h01
  k_gemm8<<<dim3(256), dim3(512), 0, stream>>>(
      x01b, 1024, o01, 1024, 16, Wf1t,
      bf1, nullptr, 2048, 1.f, 1.f, h01, 2048, 2048, 8, nullptr);

  // LayerNorm + GeLU in place (one row per wave)
  k_ln_gelu<<<dim3(2048), blk, 0, stream>>>(h01, gamma, beta);

  // FFN2 + residual (deep-prefetch 256x128) -> fp32 outputs
  k_gemm8h<false><<<dim3(256), dim3(512), 0, stream>>>(
      h01, 2048, Wf2t, bf2, x0, x1, 4096, y, 1024, 2048, 8);
}

// Round 14
// 277.791 us; speedup vs baseline: 1.2482x; 1.0108x over previous
//
#include <hip/hip_runtime.h>
#include <hip/hip_bf16.h>

typedef unsigned short u16;
typedef unsigned int u32;
typedef __attribute__((ext_vector_type(8))) short bf16x8;
typedef __attribute__((ext_vector_type(4))) float f32x4;
typedef __attribute__((ext_vector_type(16))) float f32x16;

#define DEV __device__ __forceinline__
#define FENCE asm volatile("" ::: "memory")
#define WAITL asm volatile("s_waitcnt lgkmcnt(0)" ::: "memory")
#define BAR __builtin_amdgcn_s_barrier()
#define VMC(n) asm volatile("s_waitcnt vmcnt(" #n ")" ::: "memory")

static constexpr int Bc = 4, Nc = 1024, Dc = 1024, Hc = 16, Mc = 4096, D2c = 2048;
static constexpr size_t VT_STRIDE = (size_t)4 * 16 * 64 * 1024;  // per-stream vt elems

DEV u16 f2bf(float f) {
  u32 u = __builtin_bit_cast(u32, f);
  u = (u + 0x7FFFu + ((u >> 16) & 1u)) >> 16;
  return (u16)u;
}
DEV float bf2f(u16 h) { u32 u = ((u32)h) << 16; return __builtin_bit_cast(float, u); }
DEV void gl_lds16(const void* g, void* l) {
  __builtin_amdgcn_global_load_lds((const __attribute__((address_space(1))) u32*)g,
                                   (__attribute__((address_space(3))) u32*)l, 16, 0, 0);
}
// deep swizzle for k_attn: separates rows 8 apart (row-stride 128B == bank cycle)
DEV int SW(int r, int c) { return c ^ (r & 7) ^ ((r >> 3) & 3); }

// exact-class erf: Abramowitz-Stegun 7.1.26, |err| < 1.5e-7
DEV float erf_fast(float x) {
  float ax = __builtin_fabsf(x);
  float t = __builtin_amdgcn_rcpf(__builtin_fmaf(0.3275911f, ax, 1.0f));
  float p = __builtin_fmaf(1.061405429f, t, -1.453152027f);
  p = __builtin_fmaf(p, t, 1.421413741f);
  p = __builtin_fmaf(p, t, -0.284496736f);
  p = __builtin_fmaf(p, t, 0.254829592f);
  p *= t;
  float e = __builtin_amdgcn_exp2f(-1.4426950408889634f * ax * ax);  // exp(-x^2)
  float r = __builtin_fmaf(-p, e, 1.0f);
  return __builtin_copysignf(r, x);
}
DEV float gelu_exact(float v) {
  return 0.5f * v * (1.0f + erf_fast(v * 0.70710678118654752f));
}

// ---------------- fp32 -> bf16 convert (vectorized) ----------------
__global__ __launch_bounds__(256) void k_f32_to_bf16(const float* __restrict__ in,
                                                     u16* __restrict__ out, int n) {
  int i = (blockIdx.x * 256 + threadIdx.x) * 8;
  if (i >= n) return;
  float4 a = *(const float4*)(in + i);
  float4 b = *(const float4*)(in + i + 4);
  union { u16 s[8]; uint4 v; } r;
  r.s[0] = f2bf(a.x); r.s[1] = f2bf(a.y); r.s[2] = f2bf(a.z); r.s[3] = f2bf(a.w);
  r.s[4] = f2bf(b.x); r.s[5] = f2bf(b.y); r.s[6] = f2bf(b.z); r.s[7] = f2bf(b.w);
  *(uint4*)(out + i) = r.v;
}

// ---------------- fp32 [R][C] -> bf16 [C][R] transpose-convert ----------------
__global__ __launch_bounds__(256) void k_transpose_f32_bf16(const float* __restrict__ in,
                                                            u16* __restrict__ out, int R, int C) {
  __shared__ float t[64][65];
  int c0 = blockIdx.x * 64, r0 = blockIdx.y * 64;
  int tid = threadIdx.x;
  int rr = tid >> 4, cc4 = (tid & 15) * 4;
  for (int k = 0; k < 4; ++k) {
    int r = rr + k * 16;
    float4 v = *(const float4*)(in + (size_t)(r0 + r) * C + c0 + cc4);
    t[r][cc4 + 0] = v.x; t[r][cc4 + 1] = v.y; t[r][cc4 + 2] = v.z; t[r][cc4 + 3] = v.w;
  }
  __syncthreads();
  int cw = tid >> 4, rr4 = (tid & 15) * 4;
  for (int k = 0; k < 4; ++k) {
    int c = cw + k * 16;
    union { u16 s[4]; uint2 v; } p;
    for (int j = 0; j < 4; ++j) p.s[j] = f2bf(t[rr4 + j][c]);
    *(uint2*)(out + (size_t)(c0 + c) * R + r0 + rr4) = p.v;
  }
}

// ---------------- 256x256x64 8-phase GEMM, deep-prefetch counted-vmcnt schedule ----------------
// (round-11 proven structure). vt_out: blocks with n0 >= Nsplit write their entire
// output transposed per-head into vt via an LDS re-transpose epilogue (coalesced stores).
__global__ __launch_bounds__(512, 1) void k_gemm8(
    const u16* __restrict__ A1, int lda1, const u16* __restrict__ A2, int lda2, int kstile,
    const u16* __restrict__ Bt, const float* __restrict__ bias1, const float* __restrict__ bias2,
    int Nsplit, float scale1, float scale2, u16* __restrict__ out, int ldc, int K, int gx,
    u16* __restrict__ vt_out) {
  __shared__ __align__(16) u16 lds[65536];  // [A|B][buf][half][128*64]; epilogue: [128][136] tile
  int tid = threadIdx.x;
  int w = tid >> 6, l = tid & 63;
  int lo = l & 15, hi = l >> 4;
  int wm2 = w >> 2, wn4 = w & 3;
  int nt = K >> 6, niter = nt >> 1;

  int nwg = gridDim.x;
  int swz = (blockIdx.x & 7) * (nwg >> 3) + (blockIdx.x >> 3);
  int m0 = (swz / gx) * 256, n0 = (swz % gx) * 256;

  auto ldsA = [&](int buf, int h) -> u16* { return lds + ((buf << 1) + h) * 8192; };
  auto ldsB = [&](int buf, int h) -> u16* { return lds + 32768 + ((buf << 1) + h) * 8192; };

  auto stageA = [&](int tile, int h) {
    int tt = tile < nt ? tile : 0;
    const u16* base; int ldx, kof;
    if (tt < kstile) { base = A1; ldx = lda1; kof = tt * 64; }
    else             { base = A2; ldx = lda2; kof = (tt - kstile) * 64; }
    u16* dst = ldsA(tile & 1, h);
    size_t row0 = (size_t)(m0 + h * 128);
#pragma unroll
    for (int i = 0; i < 2; ++i) {
      int e = i * 4096 + tid * 8;
      int r = e >> 6, s = (e >> 3) & 7;
      gl_lds16(base + (row0 + r) * (size_t)ldx + kof + 8 * (s ^ (r & 7)), dst + e);
    }
  };
  auto stageB = [&](int tile, int h) {
    int tt = tile < nt ? tile : 0;
    u16* dst = ldsB(tile & 1, h);
    size_t row0 = (size_t)(n0 + h * 128);
#pragma unroll
    for (int i = 0; i < 2; ++i) {
      int e = i * 4096 + tid * 8;
      int r = e >> 6, s = (e >> 3) & 7;
      gl_lds16(Bt + (row0 + r) * (size_t)K + tt * 64 + 8 * (s ^ (r & 7)), dst + e);
    }
  };
  auto loadA = [&](bf16x8 (&a)[4][2], int buf, int qm) {
    const u16* src = ldsA(buf, qm);
#pragma unroll
    for (int mf = 0; mf < 4; ++mf) {
      int r = wm2 * 64 + mf * 16 + lo;
#pragma unroll
      for (int kk = 0; kk < 2; ++kk)
        a[mf][kk] = *(const bf16x8*)&src[r * 64 + (((kk * 4 + hi) ^ (r & 7)) << 3)];
    }
  };
  auto loadB = [&](bf16x8 (&bq)[2][2], int buf, int qn) {
    const u16* src = ldsB(buf, qn);
#pragma unroll
    for (int nf = 0; nf < 2; ++nf) {
      int r = wn4 * 32 + nf * 16 + lo;
#pragma unroll
      for (int kk = 0; kk < 2; ++kk)
        bq[nf][kk] = *(const bf16x8*)&src[r * 64 + (((kk * 4 + hi) ^ (r & 7)) << 3)];
    }
  };

  f32x4 acc00[4][2] = {}, acc01[4][2] = {}, acc10[4][2] = {}, acc11[4][2] = {};
  bf16x8 a[4][2], b0[2][2], b1[2][2];

  auto mmaQ = [&](f32x4 (&accq)[4][2], bf16x8 (&aa)[4][2], bf16x8 (&bb)[2][2]) {
    __builtin_amdgcn_s_setprio(1);
#pragma unroll
    for (int mf = 0; mf < 4; ++mf)
#pragma unroll
      for (int nf = 0; nf < 2; ++nf)
#pragma unroll
        for (int kk = 0; kk < 2; ++kk)
          accq[mf][nf] = __builtin_amdgcn_mfma_f32_16x16x32_bf16(aa[mf][kk], bb[nf][kk], accq[mf][nf], 0, 0, 0);
    __builtin_amdgcn_s_setprio(0);
  };

  // prologue = virtual previous iteration's stage order
  stageA(0, 0); stageB(0, 0); stageB(0, 1); stageA(0, 1);
  stageA(1, 0); stageB(1, 0); stageB(1, 1); stageA(1, 1);
  VMC(12); BAR;

  for (int it = 0; it < niter; ++it) {
    int t0 = 2 * it;
    // PH1: buf0 A.h0, B.h0
    loadA(a, 0, 0); loadB(b0, 0, 0);
    FENCE; BAR; WAITL;
    mmaQ(acc00, a, b0);
    FENCE; VMC(10); BAR;
    // PH2: buf0 B.h1 ; stage A(t+2,0)
    loadB(b1, 0, 1);
    stageA(t0 + 2, 0);
    FENCE; BAR; WAITL;
    mmaQ(acc01, a, b1);
    FENCE; VMC(10); BAR;
    // PH3: buf0 A.h1 ; stage B(t+2,0)
    loadA(a, 0, 1);
    stageB(t0 + 2, 0);
    FENCE; BAR; WAITL;
    mmaQ(acc10, a, b0);
    FENCE; BAR;
    // PH4: regs ; stage B(t+2,1)
    stageB(t0 + 2, 1);
    FENCE; BAR;
    mmaQ(acc11, a, b1);
    FENCE; VMC(10); BAR;
    // PH5: buf1 A.h0, B.h0 ; stage A(t+2,1)
    loadA(a, 1, 0); loadB(b0, 1, 0);
    stageA(t0 + 2, 1);
    FENCE; BAR; WAITL;
    mmaQ(acc00, a, b0);
    FENCE; VMC(10); BAR;
    // PH6: buf1 B.h1 ; stage A(t+3,0)
    loadB(b1, 1, 1);
    stageA(t0 + 3, 0);
    FENCE; BAR; WAITL;
    mmaQ(acc01, a, b1);
    FENCE; VMC(10); BAR;
    // PH7: buf1 A.h1 ; stage B(t+3,0)
    loadA(a, 1, 1);
    stageB(t0 + 3, 0);
    FENCE; BAR; WAITL;
    mmaQ(acc10, a, b0);
    FENCE; BAR;
    // PH8: regs ; stage B(t+3,1), A(t+3,1)
    stageB(t0 + 3, 1); stageA(t0 + 3, 1);
    FENCE; BAR;
    mmaQ(acc11, a, b1);
    FENCE; VMC(12); BAR;
  }

  if (vt_out && n0 >= Nsplit) {
    // V-block: LDS re-transpose epilogue -> coalesced vt stores.
    VMC(0); BAR;  // drain outstanding prefetches into LDS, all waves done with staging
    int z = m0 >> 12, b = (m0 >> 10) & 3, nbase = m0 & 1023;
    auto vpass = [&](f32x4 (&accq)[4][2], int qm, int qn) {
      // store quadrant to lds tile [128 d][136 m] (pad 8 -> bank-stride 4, 2-way free)
#pragma unroll
      for (int mf = 0; mf < 4; ++mf)
#pragma unroll
        for (int nf = 0; nf < 2; ++nf) {
          int dl = wn4 * 32 + nf * 16 + lo;
          int dg = (n0 - Nsplit) + qn * 128 + dl;
          float bb = bias2[dg];
          int mp = wm2 * 64 + mf * 16 + hi * 4;
          union { u16 s[4]; uint2 v; } pk;
#pragma unroll
          for (int i = 0; i < 4; ++i) pk.s[i] = f2bf((accq[mf][nf][i] + bb) * scale2);
          *(uint2*)&lds[dl * 136 + mp] = pk.v;
        }
      BAR;
      // cooperative coalesced write: 128 d-rows x 128 m (256B contiguous per row)
#pragma unroll
      for (int itp = 0; itp < 4; ++itp) {
        int g = itp * 512 + tid;
        int dl = g >> 4, ch = g & 15;
        uint4 vv = *(const uint4*)&lds[dl * 136 + ch * 8];
        int dg = (n0 - Nsplit) + qn * 128 + dl;
        int bh = b * 16 + (dg >> 6), dd = dg & 63;
        *(uint4*)(vt_out + (size_t)z * VT_STRIDE + ((size_t)bh * 64 + dd) * 1024 +
                  nbase + qm * 128 + ch * 8) = vv;
      }
      BAR;
    };
    vpass(acc00, 0, 0); vpass(acc10, 1, 0); vpass(acc01, 0, 1); vpass(acc11, 1, 1);
  } else {
    auto epi = [&](f32x4 (&accq)[4][2], int qm, int qn) {
#pragma unroll
      for (int mf = 0; mf < 4; ++mf)
#pragma unroll
        for (int nf = 0; nf < 2; ++nf) {
          int col = n0 + qn * 128 + wn4 * 32 + nf * 16 + lo;
          float bb, sc;
          if (col < Nsplit) { bb = bias1[col]; sc = scale1; }
          else              { bb = bias2[col - Nsplit]; sc = scale2; }
          int row = m0 + qm * 128 + wm2 * 64 + mf * 16 + hi * 4;
#pragma unroll
          for (int i = 0; i < 4; ++i)
            out[(size_t)(row + i) * ldc + col] = f2bf((accq[mf][nf][i] + bb) * sc);
        }
    };
    epi(acc00, 0, 0); epi(acc01, 0, 1); epi(acc10, 1, 0); epi(acc11, 1, 1);
  }
}

// ---------------- 256x128x64 8-phase GEMM variant (round-11 proven structure) ----------------
template <bool OUT_BF16>
__global__ __launch_bounds__(512, 1) void k_gemm8h(
    const u16* __restrict__ A1, int lda1, const u16* __restrict__ Bt,
    const float* __restrict__ bias,
    const float* __restrict__ resid0, const float* __restrict__ resid1, int Msplit,
    void* __restrict__ out, int ldc, int K, int gx) {
  __shared__ __align__(16) u16 lds[49152];  // A: 2buf*2half*8192, B: 2buf*2half*4096
  int tid = threadIdx.x;
  int w = tid >> 6, l = tid & 63;
  int lo = l & 15, hi = l >> 4;
  int wm2 = w >> 2, wn4 = w & 3;
  int nt = K >> 6, niter = nt >> 1;

  int nwg = gridDim.x;
  int swz = (blockIdx.x & 7) * (nwg >> 3) + (blockIdx.x >> 3);
  int m0 = (swz / gx) * 256, n0 = (swz % gx) * 128;

  auto ldsA = [&](int buf, int h) -> u16* { return lds + ((buf << 1) + h) * 8192; };
  auto ldsB = [&](int buf, int h) -> u16* { return lds + 32768 + ((buf << 1) + h) * 4096; };

  auto stageA = [&](int tile, int h) {
    int tt = tile < nt ? tile : 0;
    u16* dst = ldsA(tile & 1, h);
    size_t row0 = (size_t)(m0 + h * 128);
#pragma unroll
    for (int i = 0; i < 2; ++i) {
      int e = i * 4096 + tid * 8;
      int r = e >> 6, s = (e >> 3) & 7;
      gl_lds16(A1 + (row0 + r) * (size_t)lda1 + tt * 64 + 8 * (s ^ (r & 7)), dst + e);
    }
  };
  auto stageB = [&](int tile, int h) {
    int tt = tile < nt ? tile : 0;
    u16* dst = ldsB(tile & 1, h);
    size_t row0 = (size_t)(n0 + h * 64);
    int e = tid * 8;
    int r = e >> 6, s = (e >> 3) & 7;
    gl_lds16(Bt + (row0 + r) * (size_t)K + tt * 64 + 8 * (s ^ (r & 7)), dst + e);
  };
  auto loadA = [&](bf16x8 (&a)[4][2], int buf, int qm) {
    const u16* src = ldsA(buf, qm);
#pragma unroll
    for (int mf = 0; mf < 4; ++mf) {
      int r = wm2 * 64 + mf * 16 + lo;
#pragma unroll
      for (int kk = 0; kk < 2; ++kk)
        a[mf][kk] = *(const bf16x8*)&src[r * 64 + (((kk * 4 + hi) ^ (r & 7)) << 3)];
    }
  };
  auto loadB = [&](bf16x8 (&bq)[2], int buf, int qn) {
    const u16* src = ldsB(buf, qn);
    int r = wn4 * 16 + lo;
#pragma unroll
    for (int kk = 0; kk < 2; ++kk)
      bq[kk] = *(const bf16x8*)&src[r * 64 + (((kk * 4 + hi) ^ (r & 7)) << 3)];
  };

  f32x4 acc00[4] = {}, acc01[4] = {}, acc10[4] = {}, acc11[4] = {};
  bf16x8 a[4][2], b0[2], b1[2];

  auto mma8 = [&](f32x4 (&accq)[4], bf16x8 (&aa)[4][2], bf16x8 (&bb)[2]) {
    __builtin_amdgcn_s_setprio(1);
#pragma unroll
    for (int mf = 0; mf < 4; ++mf)
#pragma unroll
      for (int kk = 0; kk < 2; ++kk)
        accq[mf] = __builtin_amdgcn_mfma_f32_16x16x32_bf16(aa[mf][kk], bb[kk], accq[mf], 0, 0, 0);
    __builtin_amdgcn_s_setprio(0);
  };

  // prologue = virtual previous iteration's stage order
  stageA(0, 0); stageB(0, 0); stageB(0, 1); stageA(0, 1);
  stageA(1, 0); stageB(1, 0); stageB(1, 1); stageA(1, 1);
  VMC(9); BAR;

  for (int it = 0; it < niter; ++it) {
    int t0 = 2 * it;
    // PH1
    loadA(a, 0, 0); loadB(b0, 0, 0);
    FENCE; BAR; WAITL;
    mma8(acc00, a, b0);
    FENCE; VMC(8); BAR;
    // PH2 ; stage A(t+2,0)
    loadB(b1, 0, 1);
    stageA(t0 + 2, 0);
    FENCE; BAR; WAITL;
    mma8(acc01, a, b1);
    FENCE; VMC(8); BAR;
    // PH3 ; stage B(t+2,0)
    loadA(a, 0, 1);
    stageB(t0 + 2, 0);
    FENCE; BAR; WAITL;
    mma8(acc10, a, b0);
    FENCE; BAR;
    // PH4 ; stage B(t+2,1)
    stageB(t0 + 2, 1);
    FENCE; BAR;
    mma8(acc11, a, b1);
    FENCE; VMC(7); BAR;
    // PH5 ; stage A(t+2,1)
    loadA(a, 1, 0); loadB(b0, 1, 0);
    stageA(t0 + 2, 1);
    FENCE; BAR; WAITL;
    mma8(acc00, a, b0);
    FENCE; VMC(8); BAR;
    // PH6 ; stage A(t+3,0)
    loadB(b1, 1, 1);
    stageA(t0 + 3, 0);
    FENCE; BAR; WAITL;
    mma8(acc01, a, b1);
    FENCE; VMC(8); BAR;
    // PH7 ; stage B(t+3,0)
    loadA(a, 1, 1);
    stageB(t0 + 3, 0);
    FENCE; BAR; WAITL;
    mma8(acc10, a, b0);
    FENCE; BAR;
    // PH8 ; stage B(t+3,1), A(t+3,1)
    stageB(t0 + 3, 1); stageA(t0 + 3, 1);
    FENCE; BAR;
    mma8(acc11, a, b1);
    FENCE; VMC(9); BAR;
  }

  auto epi = [&](f32x4 (&accq)[4], int qm, int qn) {
    int col = n0 + qn * 64 + wn4 * 16 + lo;
    float bb = bias[col];
#pragma unroll
    for (int mf = 0; mf < 4; ++mf) {
      int row = m0 + qm * 128 + wm2 * 64 + mf * 16 + hi * 4;
      const float* rsd = nullptr; int roff = 0;
      if (resid0) { if (row < Msplit) { rsd = resid0; } else { rsd = resid1; roff = Msplit; } }
#pragma unroll
      for (int i = 0; i < 4; ++i) {
        float v = accq[mf][i] + bb;
        if (rsd) v += rsd[(size_t)(row + i - roff) * ldc + col];
        if (OUT_BF16) ((u16*)out)[(size_t)(row + i) * ldc + col] = f2bf(v);
        else          ((float*)out)[(size_t)(row + i) * ldc + col] = v;
      }
    }
  };
  epi(acc00, 0, 0); epi(acc01, 0, 1); epi(acc10, 1, 0); epi(acc11, 1, 1);
}

// ---------------- flash attention: 8 waves x 32q, 32x32x16 MFMA, P in-register ----------------
__global__ __launch_bounds__(512, 2) void k_attn(const u16* __restrict__ qkv,
                                                 const u16* __restrict__ vt01,
                                                 u16* __restrict__ m01) {
  __shared__ __align__(16) u16 q_lds[256 * 64];
  __shared__ __align__(16) u16 k_lds[2][64 * 64];
  __shared__ __align__(16) u16 v_lds[2][64 * 64];
  int z = blockIdx.z;
  const u16* Q  = qkv + (size_t)z * Mc * 2048;
  const u16* Kg = qkv + (size_t)(1 - z) * Mc * 2048;
  const u16* Vt = vt01 + (size_t)(1 - z) * VT_STRIDE;
  u16* Out = m01 + (size_t)z * Mc * Dc;
  int tid = threadIdx.x;
  int w = tid >> 6, l = tid & 63;
  int q31 = l & 31, h = l >> 5;
  int qt = blockIdx.x;
  int bh = blockIdx.y, b = bh >> 4, hd = bh & 15;
  size_t rowQ0 = (size_t)b * Nc + qt * 256;

  {
    int r = tid >> 3, s = tid & 7;
#pragma unroll
    for (int c = 0; c < 4; ++c)
      gl_lds16(Q + (rowQ0 + c * 64 + r) * 2048 + hd * 64 + 8 * SW(r, s),
               &q_lds[(size_t)(c * 512 + tid) * 8]);
    gl_lds16(Kg + ((size_t)b * Nc + r) * 2048 + hd * 64 + 8 * SW(r, s), &k_lds[0][(size_t)tid * 8]);
    gl_lds16(Vt + ((size_t)bh * 64 + r) * Nc + 8 * SW(r, s), &v_lds[0][(size_t)tid * 8]);
  }
  __syncthreads();

  bf16x8 qf[4];
  {
    int row = w * 32 + q31;
#pragma unroll
    for (int dk = 0; dk < 4; ++dk)
      qf[dk] = *(const bf16x8*)&q_lds[row * 64 + (SW(row, dk * 2 + h) << 3)];
  }

  f32x16 o0 = {}, o1 = {};
  float ls = 0.f;
  int cur = 0;

  for (int t = 0; t < Nc / 64; ++t) {
    if (t + 1 < Nc / 64) {
      int r = tid >> 3, s = tid & 7;
      gl_lds16(Kg + ((size_t)b * Nc + (t + 1) * 64 + r) * 2048 + hd * 64 + 8 * SW(r, s),
               &k_lds[cur ^ 1][(size_t)tid * 8]);
      gl_lds16(Vt + ((size_t)bh * 64 + r) * Nc + (t + 1) * 64 + 8 * SW(r, s),
               &v_lds[cur ^ 1][(size_t)tid * 8]);
    }

    f32x16 s0 = {}, s1 = {};
    __builtin_amdgcn_s_setprio(1);
#pragma unroll
    for (int dk = 0; dk < 4; ++dk) {
      int r0 = q31, r1 = 32 + q31;
      bf16x8 k0 = *(const bf16x8*)&k_lds[cur][r0 * 64 + (SW(r0, dk * 2 + h) << 3)];
      bf16x8 k1 = *(const bf16x8*)&k_lds[cur][r1 * 64 + (SW(r1, dk * 2 + h) << 3)];
      s0 = __builtin_amdgcn_mfma_f32_32x32x16_bf16(k0, qf[dk], s0, 0, 0, 0);
      s1 = __builtin_amdgcn_mfma_f32_32x32x16_bf16(k1, qf[dk], s1, 0, 0, 0);
    }
    __builtin_amdgcn_s_setprio(0);

    // softmax without max subtraction: p = exp2(s); sum via log-depth tree + permlane
    {
      float c16[16];
#pragma unroll
      for (int i = 0; i < 16; ++i) {
        float p0 = exp2f(s0[i]);
        float p1 = exp2f(s1[i]);
        s0[i] = p0; s1[i] = p1;
        c16[i] = p0 + p1;
      }
#pragma unroll
      for (int st = 8; st >= 1; st >>= 1)
#pragma unroll
        for (int i = 0; i < st; ++i) c16[i] += c16[i + st];
      u32 xa = __builtin_bit_cast(u32, c16[0]), xb = xa;
      asm("v_permlane32_swap_b32 %0, %1" : "+v"(xa), "+v"(xb));
      ls += __builtin_bit_cast(float, xa) + __builtin_bit_cast(float, xb);
    }

    u32 pk0[4][2], pk1[4][2];
#pragma unroll
    for (int a2 = 0; a2 < 4; ++a2)
#pragma unroll
      for (int c2 = 0; c2 < 2; ++c2) {
        asm("v_cvt_pk_bf16_f32 %0, %1, %2" : "=v"(pk0[a2][c2]) : "v"(s0[4 * a2 + 2 * c2]), "v"(s0[4 * a2 + 2 * c2 + 1]));
        asm("v_cvt_pk_bf16_f32 %0, %1, %2" : "=v"(pk1[a2][c2]) : "v"(s1[4 * a2 + 2 * c2]), "v"(s1[4 * a2 + 2 * c2 + 1]));
      }
    bf16x8 pf[4];
#pragma unroll
    for (int ks = 0; ks < 4; ++ks) {
      const int aE = (2 * ks) & 3, aO = (2 * ks + 1) & 3;
      u32 x0, y0, x1, y1;
      if (ks < 2) { x0 = pk0[aE][0]; y0 = pk0[aO][0]; x1 = pk0[aE][1]; y1 = pk0[aO][1]; }
      else        { x0 = pk1[aE][0]; y0 = pk1[aO][0]; x1 = pk1[aE][1]; y1 = pk1[aO][1]; }
      asm("v_permlane32_swap_b32 %0, %1" : "+v"(x0), "+v"(y0));
      asm("v_permlane32_swap_b32 %0, %1" : "+v"(x1), "+v"(y1));
      union { u32 u[4]; bf16x8 v; } fu;
      fu.u[0] = x0; fu.u[1] = x1; fu.u[2] = y0; fu.u[3] = y1;
      pf[ks] = fu.v;
    }

    __builtin_amdgcn_s_setprio(1);
#pragma unroll
    for (int ks = 0; ks < 4; ++ks) {
      int r0 = q31, r1 = 32 + q31;
      bf16x8 v0 = *(const bf16x8*)&v_lds[cur][r0 * 64 + (SW(r0, ks * 2 + h) << 3)];
      bf16x8 v1 = *(const bf16x8*)&v_lds[cur][r1 * 64 + (SW(r1, ks * 2 + h) << 3)];
      o0 = __builtin_amdgcn_mfma_f32_32x32x16_bf16(v0, pf[ks], o0, 0, 0, 0);
      o1 = __builtin_amdgcn_mfma_f32_32x32x16_bf16(v1, pf[ks], o1, 0, 0, 0);
    }
    __builtin_amdgcn_s_setprio(0);

    __syncthreads();
    cur ^= 1;
  }

  float inv = 1.f / ls;
  int q_abs = qt * 256 + w * 32 + q31;
  u16* orow = Out + ((size_t)b * Nc + q_abs) * Dc + hd * 64;
#pragma unroll
  for (int rq = 0; rq < 4; ++rq) {
    union { u16 s[4]; uint2 v; } p0, p1;
#pragma unroll
    for (int c = 0; c < 4; ++c) {
      p0.s[c] = f2bf(o0[4 * rq + c] * inv);
      p1.s[c] = f2bf(o1[4 * rq + c] * inv);
    }
    *(uint2*)(orow + 8 * rq + 4 * h) = p0.v;
    *(uint2*)(orow + 32 + 8 * rq + 4 * h) = p1.v;
  }
}

// ---------------- LayerNorm + exact-class GeLU: one row per WAVE ----------------
__global__ __launch_bounds__(256) void k_ln_gelu(u16* __restrict__ hbuf,
                                                 const float* __restrict__ gamma,
                                                 const float* __restrict__ beta) {
  int w = threadIdx.x >> 6, l = threadIdx.x & 63;
  int row = blockIdx.x * 4 + w;
  u16* hp = hbuf + (size_t)row * D2c;

  uint4 raw[4];
#pragma unroll
  for (int i = 0; i < 4; ++i)
    raw[i] = *(const uint4*)(hp + (i * 64 + l) * 8);

  float vals[32];
  float s = 0.f, s2 = 0.f;
#pragma unroll
  for (int i = 0; i < 4; ++i) {
    const u16* rs = (const u16*)&raw[i];
#pragma unroll
    for (int j = 0; j < 8; ++j) {
      float v = bf2f(rs[j]);
      vals[i * 8 + j] = v;
      s += v; s2 += v * v;
    }
  }
#pragma unroll
  for (int off = 1; off < 64; off <<= 1) {
    s += __shfl_xor(s, off);
    s2 += __shfl_xor(s2, off);
  }
  float mu = s * (1.f / D2c);
  float var = s2 * (1.f / D2c) - mu * mu;
  float rstd = rsqrtf(var + 1e-5f);

#pragma unroll
  for (int i = 0; i < 4; ++i) {
    int cbase = (i * 64 + l) * 8;
    float4 g0 = *(const float4*)(gamma + cbase);
    float4 g1 = *(const float4*)(gamma + cbase + 4);
    float4 b0 = *(const float4*)(beta + cbase);
    float4 b1 = *(const float4*)(beta + cbase + 4);
    float g[8] = {g0.x, g0.y, g0.z, g0.w, g1.x, g1.y, g1.z, g1.w};
    float bt[8] = {b0.x, b0.y, b0.z, b0.w, b1.x, b1.y, b1.z, b1.w};
    union { u16 s[8]; uint4 v; } o;
#pragma unroll
    for (int j = 0; j < 8; ++j) {
      float v = (vals[i * 8 + j] - mu) * rstd * g[j] + bt[j];
      o.s[j] = f2bf(gelu_exact(v));
    }
    *(uint4*)(hp + cbase) = o.v;
  }
}

extern "C" void kernel_launch(void* const* d_in, const int* in_sizes, int n_in,
                              void* d_out, int out_size, void* d_ws, size_t ws_size,
                              hipStream_t stream) {
  const float* x0   = (const float*)d_in[0];
  const float* x1   = (const float*)d_in[1];
  const float* Wqk  = (const float*)d_in[2];
  const float* bqk  = (const float*)d_in[3];
  const float* Wv   = (const float*)d_in[4];
  const float* bv   = (const float*)d_in[5];
  const float* Wo   = (const float*)d_in[6];
  const float* bo   = (const float*)d_in[7];
  const float* Wf1  = (const float*)d_in[8];
  const float* bf1  = (const float*)d_in[9];
  const float* gamma= (const float*)d_in[10];
  const float* beta = (const float*)d_in[11];
  const float* Wf2  = (const float*)d_in[12];
  const float* bf2  = (const float*)d_in[13];
  float* y = (float*)d_out;

  char* p = (char*)d_ws;
  auto take = [&](size_t elems) { u16* r = (u16*)p; p += ((elems * 2 + 255) & ~(size_t)255); return r; };
  u16* Wqkvt = take((size_t)2048 * 1024);   // rows 0..1023 = Wqk^T, 1024..2047 = Wv^T
  u16* Wot   = take((size_t)1024 * 1024);
  u16* Wf1t  = take((size_t)2048 * 2048);
  u16* Wf2t  = take((size_t)2048 * 1024);
  u16* x01b  = take((size_t)8192 * 1024);
  u16* qkv   = take((size_t)8192 * 2048);   // later aliased as h01
  u16* vt01  = take(2 * VT_STRIDE);         // later aliased as o01
  u16* m01   = take((size_t)8192 * 1024);
  u16* h01 = qkv;   // FFN1 output (qkv dead after attention)
  u16* o01 = vt01;  // O-proj output (vt dead after attention)

  dim3 blk(256);
  // sqrt(log2(e)/8): applied to both q and k -> S is scaled by log2(e)/8 (exp2-domain softmax)
  const float sq = 0.4246608984f;

  // weight transposes + input converts
  k_transpose_f32_bf16<<<dim3(16, 16), blk, 0, stream>>>(Wqk, Wqkvt, 1024, 1024);
  k_transpose_f32_bf16<<<dim3(16, 16), blk, 0, stream>>>(Wv, Wqkvt + (size_t)1024 * 1024, 1024, 1024);
  k_transpose_f32_bf16<<<dim3(16, 16), blk, 0, stream>>>(Wo, Wot, 1024, 1024);
  k_transpose_f32_bf16<<<dim3(32, 32), blk, 0, stream>>>(Wf1, Wf1t, 2048, 2048);
  k_transpose_f32_bf16<<<dim3(16, 32), blk, 0, stream>>>(Wf2, Wf2t, 2048, 1024);
  k_f32_to_bf16<<<dim3(2048), blk, 0, stream>>>(x0, x01b, 4096 * 1024);
  k_f32_to_bf16<<<dim3(2048), blk, 0, stream>>>(x1, x01b + (size_t)4096 * 1024, 4096 * 1024);

  // fused qk+v projection (deep-prefetch 256^2) with fused per-head V transpose:
  // qk half -> qkv[.][0..1023]; v half -> vt01 via LDS re-transpose (coalesced)
  k_gemm8<<<dim3(256), dim3(512), 0, stream>>>(
      x01b, 1024, x01b, 1024, 16, Wqkvt,
      bqk, bv, 1024, sq, 1.f, qkv, 2048, 1024, 8, vt01);

  // cross attention (both directions in one dispatch)
  k_attn<<<dim3(4, 64, 2), dim3(512), 0, stream>>>(qkv, vt01, m01);

  // output projection (deep-prefetch 256x128): [8192,1024] x [1024,1024] -> o01
  k_gemm8h<true><<<dim3(256), dim3(512), 0, stream>>>(
      m01, 1024, Wot, bo, nullptr, nullptr, 0, o01, 1024, 1024, 8);

  // FFN1 on concat([x, o]) (deep-prefetch 256^2): [8192,2048] x [2048,2048] -> h01
  k_gemm8<<<dim3(256), dim3(512), 0, stream>>>(
      x01b, 1024, o01, 1024, 16, Wf1t,
      bf1, nullptr, 2048, 1.f, 1.f, h01, 2048, 2048, 8, nullptr);

  // LayerNorm + GeLU in place (one row per wave)
  k_ln_gelu<<<dim3(2048), blk, 0, stream>>>(h01, gamma, beta);

  // FFN2 + residual (deep-prefetch 256x128) -> fp32 outputs
  k_gemm8h<false><<<dim3(256), dim3(512), 0, stream>>>(
      h01, 2048, Wf2t, bf2, x0, x1, 4096, y, 1024, 2048, 8);
}

// Round 15
// 277.285 us; speedup vs baseline: 1.2505x; 1.0018x over previous
//
#include <hip/hip_runtime.h>
#include <hip/hip_bf16.h>

typedef unsigned short u16;
typedef unsigned int u32;
typedef __attribute__((ext_vector_type(8))) short bf16x8;
typedef __attribute__((ext_vector_type(4))) float f32x4;
typedef __attribute__((ext_vector_type(16))) float f32x16;

#define DEV __device__ __forceinline__
#define FENCE asm volatile("" ::: "memory")
#define WAITL asm volatile("s_waitcnt lgkmcnt(0)" ::: "memory")
#define BAR __builtin_amdgcn_s_barrier()
#define VMC(n) asm volatile("s_waitcnt vmcnt(" #n ")" ::: "memory")

static constexpr int Bc = 4, Nc = 1024, Dc = 1024, Hc = 16, Mc = 4096, D2c = 2048;
static constexpr size_t VT_STRIDE = (size_t)4 * 16 * 64 * 1024;  // per-stream vt elems

DEV u16 f2bf(float f) {
  u32 u = __builtin_bit_cast(u32, f);
  u = (u + 0x7FFFu + ((u >> 16) & 1u)) >> 16;
  return (u16)u;
}
DEV float bf2f(u16 h) { u32 u = ((u32)h) << 16; return __builtin_bit_cast(float, u); }
DEV void gl_lds16(const void* g, void* l) {
  __builtin_amdgcn_global_load_lds((const __attribute__((address_space(1))) u32*)g,
                                   (__attribute__((address_space(3))) u32*)l, 16, 0, 0);
}
// deep swizzle for k_attn: separates rows 8 apart (row-stride 128B == bank cycle)
DEV int SW(int r, int c) { return c ^ (r & 7) ^ ((r >> 3) & 3); }

// exact-class erf: Abramowitz-Stegun 7.1.26, |err| < 1.5e-7
DEV float erf_fast(float x) {
  float ax = __builtin_fabsf(x);
  float t = __builtin_amdgcn_rcpf(__builtin_fmaf(0.3275911f, ax, 1.0f));
  float p = __builtin_fmaf(1.061405429f, t, -1.453152027f);
  p = __builtin_fmaf(p, t, 1.421413741f);
  p = __builtin_fmaf(p, t, -0.284496736f);
  p = __builtin_fmaf(p, t, 0.254829592f);
  p *= t;
  float e = __builtin_amdgcn_exp2f(-1.4426950408889634f * ax * ax);  // exp(-x^2)
  float r = __builtin_fmaf(-p, e, 1.0f);
  return __builtin_copysignf(r, x);
}
DEV float gelu_exact(float v) {
  return 0.5f * v * (1.0f + erf_fast(v * 0.70710678118654752f));
}

// ---------------- fp32 -> bf16 convert (vectorized) ----------------
__global__ __launch_bounds__(256) void k_f32_to_bf16(const float* __restrict__ in,
                                                     u16* __restrict__ out, int n) {
  int i = (blockIdx.x * 256 + threadIdx.x) * 8;
  if (i >= n) return;
  float4 a = *(const float4*)(in + i);
  float4 b = *(const float4*)(in + i + 4);
  union { u16 s[8]; uint4 v; } r;
  r.s[0] = f2bf(a.x); r.s[1] = f2bf(a.y); r.s[2] = f2bf(a.z); r.s[3] = f2bf(a.w);
  r.s[4] = f2bf(b.x); r.s[5] = f2bf(b.y); r.s[6] = f2bf(b.z); r.s[7] = f2bf(b.w);
  *(uint4*)(out + i) = r.v;
}

// ---------------- fp32 [R][C] -> bf16 [C][R] transpose-convert ----------------
__global__ __launch_bounds__(256) void k_transpose_f32_bf16(const float* __restrict__ in,
                                                            u16* __restrict__ out, int R, int C) {
  __shared__ float t[64][65];
  int c0 = blockIdx.x * 64, r0 = blockIdx.y * 64;
  int tid = threadIdx.x;
  int rr = tid >> 4, cc4 = (tid & 15) * 4;
  for (int k = 0; k < 4; ++k) {
    int r = rr + k * 16;
    float4 v = *(const float4*)(in + (size_t)(r0 + r) * C + c0 + cc4);
    t[r][cc4 + 0] = v.x; t[r][cc4 + 1] = v.y; t[r][cc4 + 2] = v.z; t[r][cc4 + 3] = v.w;
  }
  __syncthreads();
  int cw = tid >> 4, rr4 = (tid & 15) * 4;
  for (int k = 0; k < 4; ++k) {
    int c = cw + k * 16;
    union { u16 s[4]; uint2 v; } p;
    for (int j = 0; j < 4; ++j) p.s[j] = f2bf(t[rr4 + j][c]);
    *(uint2*)(out + (size_t)(c0 + c) * R + r0 + rr4) = p.v;
  }
}

// ---------------- 256x256x64 8-phase GEMM, deep-prefetch counted-vmcnt schedule ----------------
// vt_out: blocks with n0 >= Nsplit write output transposed per-head via LDS re-transpose.
// MFMA ordering: kk OUTER -> consecutive MFMAs hit different accumulators (dep distance 8).
__global__ __launch_bounds__(512, 1) void k_gemm8(
    const u16* __restrict__ A1, int lda1, const u16* __restrict__ A2, int lda2, int kstile,
    const u16* __restrict__ Bt, const float* __restrict__ bias1, const float* __restrict__ bias2,
    int Nsplit, float scale1, float scale2, u16* __restrict__ out, int ldc, int K, int gx,
    u16* __restrict__ vt_out) {
  __shared__ __align__(16) u16 lds[65536];  // [A|B][buf][half][128*64]; epilogue: [128][136] tile
  int tid = threadIdx.x;
  int w = tid >> 6, l = tid & 63;
  int lo = l & 15, hi = l >> 4;
  int wm2 = w >> 2, wn4 = w & 3;
  int nt = K >> 6, niter = nt >> 1;

  int nwg = gridDim.x;
  int swz = (blockIdx.x & 7) * (nwg >> 3) + (blockIdx.x >> 3);
  int m0 = (swz / gx) * 256, n0 = (swz % gx) * 256;

  auto ldsA = [&](int buf, int h) -> u16* { return lds + ((buf << 1) + h) * 8192; };
  auto ldsB = [&](int buf, int h) -> u16* { return lds + 32768 + ((buf << 1) + h) * 8192; };

  auto stageA = [&](int tile, int h) {
    int tt = tile < nt ? tile : 0;
    const u16* base; int ldx, kof;
    if (tt < kstile) { base = A1; ldx = lda1; kof = tt * 64; }
    else             { base = A2; ldx = lda2; kof = (tt - kstile) * 64; }
    u16* dst = ldsA(tile & 1, h);
    size_t row0 = (size_t)(m0 + h * 128);
#pragma unroll
    for (int i = 0; i < 2; ++i) {
      int e = i * 4096 + tid * 8;
      int r = e >> 6, s = (e >> 3) & 7;
      gl_lds16(base + (row0 + r) * (size_t)ldx + kof + 8 * (s ^ (r & 7)), dst + e);
    }
  };
  auto stageB = [&](int tile, int h) {
    int tt = tile < nt ? tile : 0;
    u16* dst = ldsB(tile & 1, h);
    size_t row0 = (size_t)(n0 + h * 128);
#pragma unroll
    for (int i = 0; i < 2; ++i) {
      int e = i * 4096 + tid * 8;
      int r = e >> 6, s = (e >> 3) & 7;
      gl_lds16(Bt + (row0 + r) * (size_t)K + tt * 64 + 8 * (s ^ (r & 7)), dst + e);
    }
  };
  auto loadA = [&](bf16x8 (&a)[4][2], int buf, int qm) {
    const u16* src = ldsA(buf, qm);
#pragma unroll
    for (int mf = 0; mf < 4; ++mf) {
      int r = wm2 * 64 + mf * 16 + lo;
#pragma unroll
      for (int kk = 0; kk < 2; ++kk)
        a[mf][kk] = *(const bf16x8*)&src[r * 64 + (((kk * 4 + hi) ^ (r & 7)) << 3)];
    }
  };
  auto loadB = [&](bf16x8 (&bq)[2][2], int buf, int qn) {
    const u16* src = ldsB(buf, qn);
#pragma unroll
    for (int nf = 0; nf < 2; ++nf) {
      int r = wn4 * 32 + nf * 16 + lo;
#pragma unroll
      for (int kk = 0; kk < 2; ++kk)
        bq[nf][kk] = *(const bf16x8*)&src[r * 64 + (((kk * 4 + hi) ^ (r & 7)) << 3)];
    }
  };

  f32x4 acc00[4][2] = {}, acc01[4][2] = {}, acc10[4][2] = {}, acc11[4][2] = {};
  bf16x8 a[4][2], b0[2][2], b1[2][2];

  // kk OUTER: 8 independent MFMAs between reuses of the same accumulator
  auto mmaQ = [&](f32x4 (&accq)[4][2], bf16x8 (&aa)[4][2], bf16x8 (&bb)[2][2]) {
    __builtin_amdgcn_s_setprio(1);
#pragma unroll
    for (int kk = 0; kk < 2; ++kk)
#pragma unroll
      for (int mf = 0; mf < 4; ++mf)
#pragma unroll
        for (int nf = 0; nf < 2; ++nf)
          accq[mf][nf] = __builtin_amdgcn_mfma_f32_16x16x32_bf16(aa[mf][kk], bb[nf][kk], accq[mf][nf], 0, 0, 0);
    __builtin_amdgcn_s_setprio(0);
  };

  // prologue = virtual previous iteration's stage order
  stageA(0, 0); stageB(0, 0); stageB(0, 1); stageA(0, 1);
  stageA(1, 0); stageB(1, 0); stageB(1, 1); stageA(1, 1);
  VMC(12); BAR;

  for (int it = 0; it < niter; ++it) {
    int t0 = 2 * it;
    // PH1: buf0 A.h0, B.h0
    loadA(a, 0, 0); loadB(b0, 0, 0);
    FENCE; BAR; WAITL;
    mmaQ(acc00, a, b0);
    FENCE; VMC(10); BAR;
    // PH2: buf0 B.h1 ; stage A(t+2,0)
    loadB(b1, 0, 1);
    stageA(t0 + 2, 0);
    FENCE; BAR; WAITL;
    mmaQ(acc01, a, b1);
    FENCE; VMC(10); BAR;
    // PH3: buf0 A.h1 ; stage B(t+2,0)
    loadA(a, 0, 1);
    stageB(t0 + 2, 0);
    FENCE; BAR; WAITL;
    mmaQ(acc10, a, b0);
    FENCE; BAR;
    // PH4: regs ; stage B(t+2,1)
    stageB(t0 + 2, 1);
    FENCE; BAR;
    mmaQ(acc11, a, b1);
    FENCE; VMC(10); BAR;
    // PH5: buf1 A.h0, B.h0 ; stage A(t+2,1)
    loadA(a, 1, 0); loadB(b0, 1, 0);
    stageA(t0 + 2, 1);
    FENCE; BAR; WAITL;
    mmaQ(acc00, a, b0);
    FENCE; VMC(10); BAR;
    // PH6: buf1 B.h1 ; stage A(t+3,0)
    loadB(b1, 1, 1);
    stageA(t0 + 3, 0);
    FENCE; BAR; WAITL;
    mmaQ(acc01, a, b1);
    FENCE; VMC(10); BAR;
    // PH7: buf1 A.h1 ; stage B(t+3,0)
    loadA(a, 1, 1);
    stageB(t0 + 3, 0);
    FENCE; BAR; WAITL;
    mmaQ(acc10, a, b0);
    FENCE; BAR;
    // PH8: regs ; stage B(t+3,1), A(t+3,1)
    stageB(t0 + 3, 1); stageA(t0 + 3, 1);
    FENCE; BAR;
    mmaQ(acc11, a, b1);
    FENCE; VMC(12); BAR;
  }

  if (vt_out && n0 >= Nsplit) {
    // V-block: LDS re-transpose epilogue -> coalesced vt stores.
    VMC(0); BAR;  // drain outstanding prefetches into LDS, all waves done with staging
    int z = m0 >> 12, b = (m0 >> 10) & 3, nbase = m0 & 1023;
    auto vpass = [&](f32x4 (&accq)[4][2], int qm, int qn) {
#pragma unroll
      for (int mf = 0; mf < 4; ++mf)
#pragma unroll
        for (int nf = 0; nf < 2; ++nf) {
          int dl = wn4 * 32 + nf * 16 + lo;
          int dg = (n0 - Nsplit) + qn * 128 + dl;
          float bb = bias2[dg];
          int mp = wm2 * 64 + mf * 16 + hi * 4;
          union { u16 s[4]; uint2 v; } pk;
#pragma unroll
          for (int i = 0; i < 4; ++i) pk.s[i] = f2bf((accq[mf][nf][i] + bb) * scale2);
          *(uint2*)&lds[dl * 136 + mp] = pk.v;
        }
      BAR;
#pragma unroll
      for (int itp = 0; itp < 4; ++itp) {
        int g = itp * 512 + tid;
        int dl = g >> 4, ch = g & 15;
        uint4 vv = *(const uint4*)&lds[dl * 136 + ch * 8];
        int dg = (n0 - Nsplit) + qn * 128 + dl;
        int bh = b * 16 + (dg >> 6), dd = dg & 63;
        *(uint4*)(vt_out + (size_t)z * VT_STRIDE + ((size_t)bh * 64 + dd) * 1024 +
                  nbase + qm * 128 + ch * 8) = vv;
      }
      BAR;
    };
    vpass(acc00, 0, 0); vpass(acc10, 1, 0); vpass(acc01, 0, 1); vpass(acc11, 1, 1);
  } else {
    auto epi = [&](f32x4 (&accq)[4][2], int qm, int qn) {
#pragma unroll
      for (int mf = 0; mf < 4; ++mf)
#pragma unroll
        for (int nf = 0; nf < 2; ++nf) {
          int col = n0 + qn * 128 + wn4 * 32 + nf * 16 + lo;
          float bb, sc;
          if (col < Nsplit) { bb = bias1[col]; sc = scale1; }
          else              { bb = bias2[col - Nsplit]; sc = scale2; }
          int row = m0 + qm * 128 + wm2 * 64 + mf * 16 + hi * 4;
#pragma unroll
          for (int i = 0; i < 4; ++i)
            out[(size_t)(row + i) * ldc + col] = f2bf((accq[mf][nf][i] + bb) * sc);
        }
    };
    epi(acc00, 0, 0); epi(acc01, 0, 1); epi(acc10, 1, 0); epi(acc11, 1, 1);
  }
}

// ---------------- 256x128x64 8-phase GEMM variant ----------------
template <bool OUT_BF16>
__global__ __launch_bounds__(512, 1) void k_gemm8h(
    const u16* __restrict__ A1, int lda1, const u16* __restrict__ Bt,
    const float* __restrict__ bias,
    const float* __restrict__ resid0, const float* __restrict__ resid1, int Msplit,
    void* __restrict__ out, int ldc, int K, int gx) {
  __shared__ __align__(16) u16 lds[49152];  // A: 2buf*2half*8192, B: 2buf*2half*4096
  int tid = threadIdx.x;
  int w = tid >> 6, l = tid & 63;
  int lo = l & 15, hi = l >> 4;
  int wm2 = w >> 2, wn4 = w & 3;
  int nt = K >> 6, niter = nt >> 1;

  int nwg = gridDim.x;
  int swz = (blockIdx.x & 7) * (nwg >> 3) + (blockIdx.x >> 3);
  int m0 = (swz / gx) * 256, n0 = (swz % gx) * 128;

  auto ldsA = [&](int buf, int h) -> u16* { return lds + ((buf << 1) + h) * 8192; };
  auto ldsB = [&](int buf, int h) -> u16* { return lds + 32768 + ((buf << 1) + h) * 4096; };

  auto stageA = [&](int tile, int h) {
    int tt = tile < nt ? tile : 0;
    u16* dst = ldsA(tile & 1, h);
    size_t row0 = (size_t)(m0 + h * 128);
#pragma unroll
    for (int i = 0; i < 2; ++i) {
      int e = i * 4096 + tid * 8;
      int r = e >> 6, s = (e >> 3) & 7;
      gl_lds16(A1 + (row0 + r) * (size_t)lda1 + tt * 64 + 8 * (s ^ (r & 7)), dst + e);
    }
  };
  auto stageB = [&](int tile, int h) {
    int tt = tile < nt ? tile : 0;
    u16* dst = ldsB(tile & 1, h);
    size_t row0 = (size_t)(n0 + h * 64);
    int e = tid * 8;
    int r = e >> 6, s = (e >> 3) & 7;
    gl_lds16(Bt + (row0 + r) * (size_t)K + tt * 64 + 8 * (s ^ (r & 7)), dst + e);
  };
  auto loadA = [&](bf16x8 (&a)[4][2], int buf, int qm) {
    const u16* src = ldsA(buf, qm);
#pragma unroll
    for (int mf = 0; mf < 4; ++mf) {
      int r = wm2 * 64 + mf * 16 + lo;
#pragma unroll
      for (int kk = 0; kk < 2; ++kk)
        a[mf][kk] = *(const bf16x8*)&src[r * 64 + (((kk * 4 + hi) ^ (r & 7)) << 3)];
    }
  };
  auto loadB = [&](bf16x8 (&bq)[2], int buf, int qn) {
    const u16* src = ldsB(buf, qn);
    int r = wn4 * 16 + lo;
#pragma unroll
    for (int kk = 0; kk < 2; ++kk)
      bq[kk] = *(const bf16x8*)&src[r * 64 + (((kk * 4 + hi) ^ (r & 7)) << 3)];
  };

  f32x4 acc00[4] = {}, acc01[4] = {}, acc10[4] = {}, acc11[4] = {};
  bf16x8 a[4][2], b0[2], b1[2];

  // kk OUTER: 4 independent MFMAs between reuses of the same accumulator
  auto mma8 = [&](f32x4 (&accq)[4], bf16x8 (&aa)[4][2], bf16x8 (&bb)[2]) {
    __builtin_amdgcn_s_setprio(1);
#pragma unroll
    for (int kk = 0; kk < 2; ++kk)
#pragma unroll
      for (int mf = 0; mf < 4; ++mf)
        accq[mf] = __builtin_amdgcn_mfma_f32_16x16x32_bf16(aa[mf][kk], bb[kk], accq[mf], 0, 0, 0);
    __builtin_amdgcn_s_setprio(0);
  };

  // prologue = virtual previous iteration's stage order
  stageA(0, 0); stageB(0, 0); stageB(0, 1); stageA(0, 1);
  stageA(1, 0); stageB(1, 0); stageB(1, 1); stageA(1, 1);
  VMC(9); BAR;

  for (int it = 0; it < niter; ++it) {
    int t0 = 2 * it;
    // PH1
    loadA(a, 0, 0); loadB(b0, 0, 0);
    FENCE; BAR; WAITL;
    mma8(acc00, a, b0);
    FENCE; VMC(8); BAR;
    // PH2 ; stage A(t+2,0)
    loadB(b1, 0, 1);
    stageA(t0 + 2, 0);
    FENCE; BAR; WAITL;
    mma8(acc01, a, b1);
    FENCE; VMC(8); BAR;
    // PH3 ; stage B(t+2,0)
    loadA(a, 0, 1);
    stageB(t0 + 2, 0);
    FENCE; BAR; WAITL;
    mma8(acc10, a, b0);
    FENCE; BAR;
    // PH4 ; stage B(t+2,1)
    stageB(t0 + 2, 1);
    FENCE; BAR;
    mma8(acc11, a, b1);
    FENCE; VMC(7); BAR;
    // PH5 ; stage A(t+2,1)
    loadA(a, 1, 0); loadB(b0, 1, 0);
    stageA(t0 + 2, 1);
    FENCE; BAR; WAITL;
    mma8(acc00, a, b0);
    FENCE; VMC(8); BAR;
    // PH6 ; stage A(t+3,0)
    loadB(b1, 1, 1);
    stageA(t0 + 3, 0);
    FENCE; BAR; WAITL;
    mma8(acc01, a, b1);
    FENCE; VMC(8); BAR;
    // PH7 ; stage B(t+3,0)
    loadA(a, 1, 1);
    stageB(t0 + 3, 0);
    FENCE; BAR; WAITL;
    mma8(acc10, a, b0);
    FENCE; BAR;
    // PH8 ; stage B(t+3,1), A(t+3,1)
    stageB(t0 + 3, 1); stageA(t0 + 3, 1);
    FENCE; BAR;
    mma8(acc11, a, b1);
    FENCE; VMC(9); BAR;
  }

  auto epi = [&](f32x4 (&accq)[4], int qm, int qn) {
    int col = n0 + qn * 64 + wn4 * 16 + lo;
    float bb = bias[col];
#pragma unroll
    for (int mf = 0; mf < 4; ++mf) {
      int row = m0 + qm * 128 + wm2 * 64 + mf * 16 + hi * 4;
      const float* rsd = nullptr; int roff = 0;
      if (resid0) { if (row < Msplit) { rsd = resid0; } else { rsd = resid1; roff = Msplit; } }
#pragma unroll
      for (int i = 0; i < 4; ++i) {
        float v = accq[mf][i] + bb;
        if (rsd) v += rsd[(size_t)(row + i - roff) * ldc + col];
        if (OUT_BF16) ((u16*)out)[(size_t)(row + i) * ldc + col] = f2bf(v);
        else          ((float*)out)[(size_t)(row + i) * ldc + col] = v;
      }
    }
  };
  epi(acc00, 0, 0); epi(acc01, 0, 1); epi(acc10, 1, 0); epi(acc11, 1, 1);
}

// ---------------- flash attention: 8 waves x 32q, 32x32x16 MFMA, P in-register ----------------
__global__ __launch_bounds__(512, 2) void k_attn(const u16* __restrict__ qkv,
                                                 const u16* __restrict__ vt01,
                                                 u16* __restrict__ m01) {
  __shared__ __align__(16) u16 q_lds[256 * 64];
  __shared__ __align__(16) u16 k_lds[2][64 * 64];
  __shared__ __align__(16) u16 v_lds[2][64 * 64];
  int z = blockIdx.z;
  const u16* Q  = qkv + (size_t)z * Mc * 2048;
  const u16* Kg = qkv + (size_t)(1 - z) * Mc * 2048;
  const u16* Vt = vt01 + (size_t)(1 - z) * VT_STRIDE;
  u16* Out = m01 + (size_t)z * Mc * Dc;
  int tid = threadIdx.x;
  int w = tid >> 6, l = tid & 63;
  int q31 = l & 31, h = l >> 5;
  int qt = blockIdx.x;
  int bh = blockIdx.y, b = bh >> 4, hd = bh & 15;
  size_t rowQ0 = (size_t)b * Nc + qt * 256;

  {
    int r = tid >> 3, s = tid & 7;
#pragma unroll
    for (int c = 0; c < 4; ++c)
      gl_lds16(Q + (rowQ0 + c * 64 + r) * 2048 + hd * 64 + 8 * SW(r, s),
               &q_lds[(size_t)(c * 512 + tid) * 8]);
    gl_lds16(Kg + ((size_t)b * Nc + r) * 2048 + hd * 64 + 8 * SW(r, s), &k_lds[0][(size_t)tid * 8]);
    gl_lds16(Vt + ((size_t)bh * 64 + r) * Nc + 8 * SW(r, s), &v_lds[0][(size_t)tid * 8]);
  }
  __syncthreads();

  bf16x8 qf[4];
  {
    int row = w * 32 + q31;
#pragma unroll
    for (int dk = 0; dk < 4; ++dk)
      qf[dk] = *(const bf16x8*)&q_lds[row * 64 + (SW(row, dk * 2 + h) << 3)];
  }

  f32x16 o0 = {}, o1 = {};
  float ls = 0.f;
  int cur = 0;

  for (int t = 0; t < Nc / 64; ++t) {
    if (t + 1 < Nc / 64) {
      int r = tid >> 3, s = tid & 7;
      gl_lds16(Kg + ((size_t)b * Nc + (t + 1) * 64 + r) * 2048 + hd * 64 + 8 * SW(r, s),
               &k_lds[cur ^ 1][(size_t)tid * 8]);
      gl_lds16(Vt + ((size_t)bh * 64 + r) * Nc + (t + 1) * 64 + 8 * SW(r, s),
               &v_lds[cur ^ 1][(size_t)tid * 8]);
    }

    f32x16 s0 = {}, s1 = {};
    __builtin_amdgcn_s_setprio(1);
#pragma unroll
    for (int dk = 0; dk < 4; ++dk) {
      int r0 = q31, r1 = 32 + q31;
      bf16x8 k0 = *(const bf16x8*)&k_lds[cur][r0 * 64 + (SW(r0, dk * 2 + h) << 3)];
      bf16x8 k1 = *(const bf16x8*)&k_lds[cur][r1 * 64 + (SW(r1, dk * 2 + h) << 3)];
      s0 = __builtin_amdgcn_mfma_f32_32x32x16_bf16(k0, qf[dk], s0, 0, 0, 0);
      s1 = __builtin_amdgcn_mfma_f32_32x32x16_bf16(k1, qf[dk], s1, 0, 0, 0);
    }
    __builtin_amdgcn_s_setprio(0);

    // softmax without max subtraction: p = exp2(s); sum via log-depth tree + permlane
    {
      float c16[16];
#pragma unroll
      for (int i = 0; i < 16; ++i) {
        float p0 = exp2f(s0[i]);
        float p1 = exp2f(s1[i]);
        s0[i] = p0; s1[i] = p1;
        c16[i] = p0 + p1;
      }
#pragma unroll
      for (int st = 8; st >= 1; st >>= 1)
#pragma unroll
        for (int i = 0; i < st; ++i) c16[i] += c16[i + st];
      u32 xa = __builtin_bit_cast(u32, c16[0]), xb = xa;
      asm("v_permlane32_swap_b32 %0, %1" : "+v"(xa), "+v"(xb));
      ls += __builtin_bit_cast(float, xa) + __builtin_bit_cast(float, xb);
    }

    u32 pk0[4][2], pk1[4][2];
#pragma unroll
    for (int a2 = 0; a2 < 4; ++a2)
#pragma unroll
      for (int c2 = 0; c2 < 2; ++c2) {
        asm("v_cvt_pk_bf16_f32 %0, %1, %2" : "=v"(pk0[a2][c2]) : "v"(s0[4 * a2 + 2 * c2]), "v"(s0[4 * a2 + 2 * c2 + 1]));
        asm("v_cvt_pk_bf16_f32 %0, %1, %2" : "=v"(pk1[a2][c2]) : "v"(s1[4 * a2 + 2 * c2]), "v"(s1[4 * a2 + 2 * c2 + 1]));
      }
    bf16x8 pf[4];
#pragma unroll
    for (int ks = 0; ks < 4; ++ks) {
      const int aE = (2 * ks) & 3, aO = (2 * ks + 1) & 3;
      u32 x0, y0, x1, y1;
      if (ks < 2) { x0 = pk0[aE][0]; y0 = pk0[aO][0]; x1 = pk0[aE][1]; y1 = pk0[aO][1]; }
      else        { x0 = pk1[aE][0]; y0 = pk1[aO][0]; x1 = pk1[aE][1]; y1 = pk1[aO][1]; }
      asm("v_permlane32_swap_b32 %0, %1" : "+v"(x0), "+v"(y0));
      asm("v_permlane32_swap_b32 %0, %1" : "+v"(x1), "+v"(y1));
      union { u32 u[4]; bf16x8 v; } fu;
      fu.u[0] = x0; fu.u[1] = x1; fu.u[2] = y0; fu.u[3] = y1;
      pf[ks] = fu.v;
    }

    __builtin_amdgcn_s_setprio(1);
#pragma unroll
    for (int ks = 0; ks < 4; ++ks) {
      int r0 = q31, r1 = 32 + q31;
      bf16x8 v0 = *(const bf16x8*)&v_lds[cur][r0 * 64 + (SW(r0, ks * 2 + h) << 3)];
      bf16x8 v1 = *(const bf16x8*)&v_lds[cur][r1 * 64 + (SW(r1, ks * 2 + h) << 3)];
      o0 = __builtin_amdgcn_mfma_f32_32x32x16_bf16(v0, pf[ks], o0, 0, 0, 0);
      o1 = __builtin_amdgcn_mfma_f32_32x32x16_bf16(v1, pf[ks], o1, 0, 0, 0);
    }
    __builtin_amdgcn_s_setprio(0);

    __syncthreads();
    cur ^= 1;
  }

  float inv = 1.f / ls;
  int q_abs = qt * 256 + w * 32 + q31;
  u16* orow = Out + ((size_t)b * Nc + q_abs) * Dc + hd * 64;
#pragma unroll
  for (int rq = 0; rq < 4; ++rq) {
    union { u16 s[4]; uint2 v; } p0, p1;
#pragma unroll
    for (int c = 0; c < 4; ++c) {
      p0.s[c] = f2bf(o0[4 * rq + c] * inv);
      p1.s[c] = f2bf(o1[4 * rq + c] * inv);
    }
    *(uint2*)(orow + 8 * rq + 4 * h) = p0.v;
    *(uint2*)(orow + 32 + 8 * rq + 4 * h) = p1.v;
  }
}

// ---------------- LayerNorm + exact-class GeLU: one row per WAVE ----------------
__global__ __launch_bounds__(256) void k_ln_gelu(u16* __restrict__ hbuf,
                                                 const float* __restrict__ gamma,
                                                 const float* __restrict__ beta) {
  int w = threadIdx.x >> 6, l = threadIdx.x & 63;
  int row = blockIdx.x * 4 + w;
  u16* hp = hbuf + (size_t)row * D2c;

  uint4 raw[4];
#pragma unroll
  for (int i = 0; i < 4; ++i)
    raw[i] = *(const uint4*)(hp + (i * 64 + l) * 8);

  float vals[32];
  float s = 0.f, s2 = 0.f;
#pragma unroll
  for (int i = 0; i < 4; ++i) {
    const u16* rs = (const u16*)&raw[i];
#pragma unroll
    for (int j = 0; j < 8; ++j) {
      float v = bf2f(rs[j]);
      vals[i * 8 + j] = v;
      s += v; s2 += v * v;
    }
  }
#pragma unroll
  for (int off = 1; off < 64; off <<= 1) {
    s += __shfl_xor(s, off);
    s2 += __shfl_xor(s2, off);
  }
  float mu = s * (1.f / D2c);
  float var = s2 * (1.f / D2c) - mu * mu;
  float rstd = rsqrtf(var + 1e-5f);

#pragma unroll
  for (int i = 0; i < 4; ++i) {
    int cbase = (i * 64 + l) * 8;
    float4 g0 = *(const float4*)(gamma + cbase);
    float4 g1 = *(const float4*)(gamma + cbase + 4);
    float4 b0 = *(const float4*)(beta + cbase);
    float4 b1 = *(const float4*)(beta + cbase + 4);
    float g[8] = {g0.x, g0.y, g0.z, g0.w, g1.x, g1.y, g1.z, g1.w};
    float bt[8] = {b0.x, b0.y, b0.z, b0.w, b1.x, b1.y, b1.z, b1.w};
    union { u16 s[8]; uint4 v; } o;
#pragma unroll
    for (int j = 0; j < 8; ++j) {
      float v = (vals[i * 8 + j] - mu) * rstd * g[j] + bt[j];
      o.s[j] = f2bf(gelu_exact(v));
    }
    *(uint4*)(hp + cbase) = o.v;
  }
}

extern "C" void kernel_launch(void* const* d_in, const int* in_sizes, int n_in,
                              void* d_out, int out_size, void* d_ws, size_t ws_size,
                              hipStream_t stream) {
  const float* x0   = (const float*)d_in[0];
  const float* x1   = (const float*)d_in[1];
  const float* Wqk  = (const float*)d_in[2];
  const float* bqk  = (const float*)d_in[3];
  const float* Wv   = (const float*)d_in[4];
  const float* bv   = (const float*)d_in[5];
  const float* Wo   = (const float*)d_in[6];
  const float* bo   = (const float*)d_in[7];
  const float* Wf1  = (const float*)d_in[8];
  const float* bf1  = (const float*)d_in[9];
  const float* gamma= (const float*)d_in[10];
  const float* beta = (const float*)d_in[11];
  const float* Wf2  = (const float*)d_in[12];
  const float* bf2  = (const float*)d_in[13];
  float* y = (float*)d_out;

  char* p = (char*)d_ws;
  auto take = [&](size_t elems) { u16* r = (u16*)p; p += ((elems * 2 + 255) & ~(size_t)255); return r; };
  u16* Wqkvt = take((size_t)2048 * 1024);   // rows 0..1023 = Wqk^T, 1024..2047 = Wv^T
  u16* Wot   = take((size_t)1024 * 1024);
  u16* Wf1t  = take((size_t)2048 * 2048);
  u16* Wf2t  = take((size_t)2048 * 1024);
  u16* x01b  = take((size_t)8192 * 1024);
  u16* qkv   = take((size_t)8192 * 2048);   // later aliased as h01
  u16* vt01  = take(2 * VT_STRIDE);         // later aliased as o01
  u16* m01   = take((size_t)8192 * 1024);
  u16* h01 = qkv;   // FFN1 output (qkv dead after attention)
  u16* o01 = vt01;  // O-proj output (vt dead after attention)

  dim3 blk(256);
  // sqrt(log2(e)/8): applied to both q and k -> S is scaled by log2(e)/8 (exp2-domain softmax)
  const float sq = 0.4246608984f;

  // weight transposes + input converts
  k_transpose_f32_bf16<<<dim3(16, 16), blk, 0, stream>>>(Wqk, Wqkvt, 1024, 1024);
  k_transpose_f32_bf16<<<dim3(16, 16), blk, 0, stream>>>(Wv, Wqkvt + (size_t)1024 * 1024, 1024, 1024);
  k_transpose_f32_bf16<<<dim3(16, 16), blk, 0, stream>>>(Wo, Wot, 1024, 1024);
  k_transpose_f32_bf16<<<dim3(32, 32), blk, 0, stream>>>(Wf1, Wf1t, 2048, 2048);
  k_transpose_f32_bf16<<<dim3(16, 32), blk, 0, stream>>>(Wf2, Wf2t, 2048, 1024);
  k_f32_to_bf16<<<dim3(2048), blk, 0, stream>>>(x0, x01b, 4096 * 1024);
  k_f32_to_bf16<<<dim3(2048), blk, 0, stream>>>(x1, x01b + (size_t)4096 * 1024, 4096 * 1024);

  // fused qk+v projection (deep-prefetch 256^2) with fused per-head V transpose
  k_gemm8<<<dim3(256), dim3(512), 0, stream>>>(
      x01b, 1024, x01b, 1024, 16, Wqkvt,
      bqk, bv, 1024, sq, 1.f, qkv, 2048, 1024, 8, vt01);

  // cross attention (both directions in one dispatch)
  k_attn<<<dim3(4, 64, 2), dim3(512), 0, stream>>>(qkv, vt01, m01);

  // output projection (deep-prefetch 256x128): [8192,1024] x [1024,1024] -> o01
  k_gemm8h<true><<<dim3(256), dim3(512), 0, stream>>>(
      m01, 1024, Wot, bo, nullptr, nullptr, 0, o01, 1024, 1024, 8);

  // FFN1 on concat([x, o]) (deep-prefetch 256^2): [8192,2048] x [2048,2048] -> h01
  k_gemm8<<<dim3(256), dim3(512), 0, stream>>>(
      x01b, 1024, o01, 1024, 16, Wf1t,
      bf1, nullptr, 2048, 1.f, 1.f, h01, 2048, 2048, 8, nullptr);

  // LayerNorm + GeLU in place (one row per wave)
  k_ln_gelu<<<dim3(2048), blk, 0, stream>>>(h01, gamma, beta);

  // FFN2 + residual (deep-prefetch 256x128) -> fp32 outputs
  k_gemm8h<false><<<dim3(256), dim3(512), 0, stream>>>(
      h01, 2048, Wf2t, bf2, x0, x1, 4096, y, 1024, 2048, 8);
}